// Round 1
// baseline (27892.621 us; speedup 1.0000x reference)
//
#include <hip/hip_runtime.h>
#include <hip/hip_bf16.h>

// Problem constants
#define LNUM 6
#define HNUM 16
#define DMODEL 768
#define FFDIM 3072
#define BATCH 4
#define NTOK 1023
#define SEQ 1024          // NTOK + 1
#define HD 48             // DMODEL / HNUM
#define EPS 1e-5f

// ---------------------------------------------------------------------------
// concat: x[b,s,:] = s==0 ? cls_token : cls_tokens[b,s-1,:]
// ---------------------------------------------------------------------------
__global__ __launch_bounds__(256) void concat_kernel(
    const float* __restrict__ cls_tokens, const float* __restrict__ cls_token,
    float* __restrict__ x) {
  size_t i = (size_t)blockIdx.x * blockDim.x + threadIdx.x;
  const size_t total = (size_t)BATCH * SEQ * DMODEL;
  if (i >= total) return;
  int d = (int)(i % DMODEL);
  size_t bs = i / DMODEL;
  int s = (int)(bs % SEQ);
  int b = (int)(bs / SEQ);
  float v;
  if (s == 0) v = cls_token[d];
  else v = cls_tokens[((size_t)b * NTOK + (s - 1)) * DMODEL + d];
  x[i] = v;
}

// ---------------------------------------------------------------------------
// layernorm: one 256-thread block per row of 768
// ---------------------------------------------------------------------------
__global__ __launch_bounds__(256) void ln_kernel(
    const float* __restrict__ in, float* __restrict__ out,
    const float* __restrict__ w, const float* __restrict__ bias,
    size_t in_stride, size_t out_stride) {
  const int row = blockIdx.x;
  const int tid = threadIdx.x;
  const float* x = in + (size_t)row * in_stride;
  float* y = out + (size_t)row * out_stride;

  float v0 = x[tid], v1 = x[tid + 256], v2 = x[tid + 512];
  float s = v0 + v1 + v2;
  float sq = v0 * v0 + v1 * v1 + v2 * v2;

  __shared__ float s_sum[256];
  __shared__ float s_sq[256];
  s_sum[tid] = s;
  s_sq[tid] = sq;
  __syncthreads();
  for (int off = 128; off > 0; off >>= 1) {
    if (tid < off) {
      s_sum[tid] += s_sum[tid + off];
      s_sq[tid] += s_sq[tid + off];
    }
    __syncthreads();
  }
  const float inv_d = 1.0f / (float)DMODEL;
  float mean = s_sum[0] * inv_d;
  float var = s_sq[0] * inv_d - mean * mean;
  float rstd = rsqrtf(var + EPS);

  y[tid]       = (v0 - mean) * rstd * w[tid]       + bias[tid];
  y[tid + 256] = (v1 - mean) * rstd * w[tid + 256] + bias[tid + 256];
  y[tid + 512] = (v2 - mean) * rstd * w[tid + 512] + bias[tid + 512];
}

// ---------------------------------------------------------------------------
// Tiled fp32 NT GEMM: C[m,n] (+)= sum_k A[m,k] * Bt[n,k]
// A: M x K row-major, Bt: N x K row-major. M,N multiples of 64; K of 16.
// 64x64 tile, 256 threads, 4x4 micro-tile per thread.
// ---------------------------------------------------------------------------
#define GTILE 64
#define GTK 16
#define GPAD 4   // LDS row stride 68 floats -> float4-aligned, conflict-light

__global__ __launch_bounds__(256) void gemm_nt(
    const float* __restrict__ A, const float* __restrict__ Bt,
    float* __restrict__ C, int M, int N, int K, int accumulate) {
  __shared__ float As[GTK][GTILE + GPAD];
  __shared__ float Bs[GTK][GTILE + GPAD];

  const int tid = threadIdx.x;
  const int m0 = blockIdx.y * GTILE;
  const int n0 = blockIdx.x * GTILE;
  const int tx = tid & 15;
  const int ty = tid >> 4;

  // loader: thread loads one float4 (4 consecutive k) from one row of A and B
  const int lm = tid >> 2;        // 0..63
  const int lk = (tid & 3) * 4;   // 0,4,8,12

  const float* Arow = A + (size_t)(m0 + lm) * K + lk;
  const float* Brow = Bt + (size_t)(n0 + lm) * K + lk;

  float acc[4][4];
#pragma unroll
  for (int i = 0; i < 4; i++)
#pragma unroll
    for (int j = 0; j < 4; j++) acc[i][j] = 0.f;

  for (int k0 = 0; k0 < K; k0 += GTK) {
    float4 av = *(const float4*)(Arow + k0);
    float4 bv = *(const float4*)(Brow + k0);
    As[lk + 0][lm] = av.x; As[lk + 1][lm] = av.y;
    As[lk + 2][lm] = av.z; As[lk + 3][lm] = av.w;
    Bs[lk + 0][lm] = bv.x; Bs[lk + 1][lm] = bv.y;
    Bs[lk + 2][lm] = bv.z; Bs[lk + 3][lm] = bv.w;
    __syncthreads();
#pragma unroll
    for (int kk = 0; kk < GTK; kk++) {
      float4 a4 = *(const float4*)(&As[kk][ty * 4]);
      float4 b4 = *(const float4*)(&Bs[kk][tx * 4]);
      float a[4] = {a4.x, a4.y, a4.z, a4.w};
      float b[4] = {b4.x, b4.y, b4.z, b4.w};
#pragma unroll
      for (int i = 0; i < 4; i++)
#pragma unroll
        for (int j = 0; j < 4; j++) acc[i][j] += a[i] * b[j];
    }
    __syncthreads();
  }

#pragma unroll
  for (int i = 0; i < 4; i++) {
    float* cp = C + (size_t)(m0 + ty * 4 + i) * N + n0 + tx * 4;
    float4 v = make_float4(acc[i][0], acc[i][1], acc[i][2], acc[i][3]);
    if (accumulate) {
      float4 old = *(const float4*)cp;
      v.x += old.x; v.y += old.y; v.z += old.z; v.w += old.w;
    }
    *(float4*)cp = v;
  }
}

// ---------------------------------------------------------------------------
// Attention: one 64-lane wave per (b, h, q). Online softmax per lane over its
// 16 keys (k = t*64 + lane), then cross-lane merge (shuffle max/sum + LDS
// transpose for the 48-dim output reduction).
// qkv layout: [B, S, 3*D]; q at h*HD, k at D + h*HD, v at 2D + h*HD.
// ---------------------------------------------------------------------------
__global__ __launch_bounds__(64) void attn_kernel(
    const float* __restrict__ qkv, const float* __restrict__ log_slopes,
    float* __restrict__ obuf) {
  const int q = blockIdx.x;
  const int h = blockIdx.y;
  const int b = blockIdx.z;
  const int lane = threadIdx.x;

  const float scale = 0.14433756729740643f;  // 1/sqrt(48)
  const float slope = __expf(log_slopes[h]);

  // load q (all lanes load full vector; same address -> broadcast via L1)
  float qr[HD];
  {
    const size_t qbase = ((size_t)(b * SEQ + q)) * (3 * DMODEL) + h * HD;
    const float4* qp = (const float4*)(qkv + qbase);
#pragma unroll
    for (int i = 0; i < HD / 4; i++) {
      float4 t = qp[i];
      qr[4 * i + 0] = t.x * scale;
      qr[4 * i + 1] = t.y * scale;
      qr[4 * i + 2] = t.z * scale;
      qr[4 * i + 3] = t.w * scale;
    }
  }

  float m = -1e30f, l = 0.f;
  float o[HD];
#pragma unroll
  for (int i = 0; i < HD; i++) o[i] = 0.f;

  for (int t = 0; t < SEQ / 64; t++) {
    const int sk = t * 64 + lane;
    const size_t kb = ((size_t)(b * SEQ + sk)) * (3 * DMODEL) + DMODEL + h * HD;
    const float4* kp = (const float4*)(qkv + kb);
    float s = 0.f;
#pragma unroll
    for (int i = 0; i < HD / 4; i++) {
      float4 kv4 = kp[i];
      s += qr[4 * i + 0] * kv4.x + qr[4 * i + 1] * kv4.y +
           qr[4 * i + 2] * kv4.z + qr[4 * i + 3] * kv4.w;
    }
    s -= slope * fabsf((float)(q - sk));

    float mnew = fmaxf(m, s);
    float corr = __expf(m - mnew);
    float p = __expf(s - mnew);
    l = l * corr + p;
    const float4* vp = (const float4*)(qkv + kb + DMODEL);
#pragma unroll
    for (int i = 0; i < HD / 4; i++) {
      float4 vv = vp[i];
      o[4 * i + 0] = o[4 * i + 0] * corr + p * vv.x;
      o[4 * i + 1] = o[4 * i + 1] * corr + p * vv.y;
      o[4 * i + 2] = o[4 * i + 2] * corr + p * vv.z;
      o[4 * i + 3] = o[4 * i + 3] * corr + p * vv.w;
    }
    m = mnew;
  }

  // global max over lanes
  float M = m;
#pragma unroll
  for (int off = 32; off > 0; off >>= 1) M = fmaxf(M, __shfl_xor(M, off, 64));
  float w = __expf(m - M);
  float lw = l * w;
  float L = lw;
#pragma unroll
  for (int off = 32; off > 0; off >>= 1) L += __shfl_xor(L, off, 64);

  // scaled partials -> LDS transpose reduce
  __shared__ float red[64][HD + 1];  // pad to 49 to break bank stride
#pragma unroll
  for (int i = 0; i < HD; i++) red[lane][i] = o[i] * w;
  __syncthreads();

  if (lane < HD) {
    float sum = 0.f;
    for (int r = 0; r < 64; r++) sum += red[r][lane];
    obuf[((size_t)(b * SEQ + q)) * DMODEL + h * HD + lane] = sum / L;
  }
}

// ---------------------------------------------------------------------------
// g = silu(g) * u
// ---------------------------------------------------------------------------
__global__ __launch_bounds__(256) void silu_mul_kernel(
    float* __restrict__ g, const float* __restrict__ u, size_t n) {
  size_t i = (size_t)blockIdx.x * blockDim.x + threadIdx.x;
  size_t stride = (size_t)gridDim.x * blockDim.x;
  for (; i < n; i += stride) {
    float gv = g[i];
    float sig = 1.0f / (1.0f + __expf(-gv));
    g[i] = gv * sig * u[i];
  }
}

// ---------------------------------------------------------------------------
// launcher
// ---------------------------------------------------------------------------
extern "C" void kernel_launch(void* const* d_in, const int* in_sizes, int n_in,
                              void* d_out, int out_size, void* d_ws, size_t ws_size,
                              hipStream_t stream) {
  const float* cls_tokens = (const float*)d_in[0];
  const float* cls_token  = (const float*)d_in[1];
  const float* log_slopes = (const float*)d_in[2];
  const float* Wqkv = (const float*)d_in[3];
  const float* Wo   = (const float*)d_in[4];
  const float* Wg   = (const float*)d_in[5];
  const float* Wu   = (const float*)d_in[6];
  const float* Wd   = (const float*)d_in[7];
  const float* ln1_w = (const float*)d_in[8];
  const float* ln1_b = (const float*)d_in[9];
  const float* ln2_w = (const float*)d_in[10];
  const float* ln2_b = (const float*)d_in[11];
  const float* fin_w = (const float*)d_in[12];
  const float* fin_b = (const float*)d_in[13];
  float* out = (float*)d_out;

  float* ws = (float*)d_ws;
  const size_t ROWS = (size_t)BATCH * SEQ;           // 4096
  float* x   = ws;                                   // 3,145,728
  float* h   = ws + (size_t)3145728;                 // 3,145,728
  float* qkv = ws + (size_t)6291456;                 // 9,437,184
  float* o   = ws + (size_t)15728640;                // 3,145,728
  float* g   = ws + (size_t)18874368;                // 12,582,912
  float* u   = ws + (size_t)6291456;                 // aliases qkv+o (dead by then)

  // build x
  {
    const size_t total = ROWS * DMODEL;
    int blocks = (int)((total + 255) / 256);
    concat_kernel<<<blocks, 256, 0, stream>>>(cls_tokens, cls_token, x);
  }

  for (int l = 0; l < LNUM; l++) {
    const float* wqkv_l = Wqkv + (size_t)l * 3 * DMODEL * DMODEL;
    const float* wo_l   = Wo + (size_t)l * DMODEL * DMODEL;
    const float* wg_l   = Wg + (size_t)l * FFDIM * DMODEL;
    const float* wu_l   = Wu + (size_t)l * FFDIM * DMODEL;
    const float* wd_l   = Wd + (size_t)l * DMODEL * FFDIM;

    // h = LN1(x)
    ln_kernel<<<(int)ROWS, 256, 0, stream>>>(x, h, ln1_w + l * DMODEL,
                                             ln1_b + l * DMODEL, DMODEL, DMODEL);
    // qkv = h @ Wqkv^T
    gemm_nt<<<dim3(3 * DMODEL / GTILE, ROWS / GTILE), 256, 0, stream>>>(
        h, wqkv_l, qkv, (int)ROWS, 3 * DMODEL, DMODEL, 0);
    // attention
    attn_kernel<<<dim3(SEQ, HNUM, BATCH), 64, 0, stream>>>(qkv, log_slopes, o);
    // x += o @ Wo^T
    gemm_nt<<<dim3(DMODEL / GTILE, ROWS / GTILE), 256, 0, stream>>>(
        o, wo_l, x, (int)ROWS, DMODEL, DMODEL, 1);
    // h = LN2(x)
    ln_kernel<<<(int)ROWS, 256, 0, stream>>>(x, h, ln2_w + l * DMODEL,
                                             ln2_b + l * DMODEL, DMODEL, DMODEL);
    // g = h @ Wg^T ; u = h @ Wu^T
    gemm_nt<<<dim3(FFDIM / GTILE, ROWS / GTILE), 256, 0, stream>>>(
        h, wg_l, g, (int)ROWS, FFDIM, DMODEL, 0);
    gemm_nt<<<dim3(FFDIM / GTILE, ROWS / GTILE), 256, 0, stream>>>(
        h, wu_l, u, (int)ROWS, FFDIM, DMODEL, 0);
    // g = silu(g) * u
    silu_mul_kernel<<<4096, 256, 0, stream>>>(g, u, ROWS * FFDIM);
    // x += g @ Wd^T
    gemm_nt<<<dim3(DMODEL / GTILE, ROWS / GTILE), 256, 0, stream>>>(
        g, wd_l, x, (int)ROWS, DMODEL, FFDIM, 1);
  }

  // out = LN(x[:, 0, :]) — row b at x + b*SEQ*DMODEL
  ln_kernel<<<BATCH, 256, 0, stream>>>(x, out, fin_w, fin_b,
                                       (size_t)SEQ * DMODEL, DMODEL);
}

// Round 2
// 8364.848 us; speedup vs baseline: 3.3345x; 3.3345x over previous
//
#include <hip/hip_runtime.h>
#include <hip/hip_bf16.h>

// Problem constants
#define LNUM 6
#define HNUM 16
#define DMODEL 768
#define FFDIM 3072
#define BATCH 4
#define NTOK 1023
#define SEQ 1024          // NTOK + 1
#define HD 48             // DMODEL / HNUM
#define EPS 1e-5f

// ---------------------------------------------------------------------------
// concat: x[b,s,:] = s==0 ? cls_token : cls_tokens[b,s-1,:]
// ---------------------------------------------------------------------------
__global__ __launch_bounds__(256) void concat_kernel(
    const float* __restrict__ cls_tokens, const float* __restrict__ cls_token,
    float* __restrict__ x) {
  size_t i = (size_t)blockIdx.x * blockDim.x + threadIdx.x;
  const size_t total = (size_t)BATCH * SEQ * DMODEL;
  if (i >= total) return;
  int d = (int)(i % DMODEL);
  size_t bs = i / DMODEL;
  int s = (int)(bs % SEQ);
  int b = (int)(bs / SEQ);
  float v;
  if (s == 0) v = cls_token[d];
  else v = cls_tokens[((size_t)b * NTOK + (s - 1)) * DMODEL + d];
  x[i] = v;
}

// ---------------------------------------------------------------------------
// layernorm: one 256-thread block per row of 768
// ---------------------------------------------------------------------------
__global__ __launch_bounds__(256) void ln_kernel(
    const float* __restrict__ in, float* __restrict__ out,
    const float* __restrict__ w, const float* __restrict__ bias,
    size_t in_stride, size_t out_stride) {
  const int row = blockIdx.x;
  const int tid = threadIdx.x;
  const float* x = in + (size_t)row * in_stride;
  float* y = out + (size_t)row * out_stride;

  float v0 = x[tid], v1 = x[tid + 256], v2 = x[tid + 512];
  float s = v0 + v1 + v2;
  float sq = v0 * v0 + v1 * v1 + v2 * v2;

  __shared__ float s_sum[256];
  __shared__ float s_sq[256];
  s_sum[tid] = s;
  s_sq[tid] = sq;
  __syncthreads();
  for (int off = 128; off > 0; off >>= 1) {
    if (tid < off) {
      s_sum[tid] += s_sum[tid + off];
      s_sq[tid] += s_sq[tid + off];
    }
    __syncthreads();
  }
  const float inv_d = 1.0f / (float)DMODEL;
  float mean = s_sum[0] * inv_d;
  float var = s_sq[0] * inv_d - mean * mean;
  float rstd = rsqrtf(var + EPS);

  y[tid]       = (v0 - mean) * rstd * w[tid]       + bias[tid];
  y[tid + 256] = (v1 - mean) * rstd * w[tid + 256] + bias[tid + 256];
  y[tid + 512] = (v2 - mean) * rstd * w[tid + 512] + bias[tid + 512];
}

// ---------------------------------------------------------------------------
// Tiled fp32 NT GEMM: C[m,n] (+)= sum_k A[m,k] * Bt[n,k]
// ---------------------------------------------------------------------------
#define GTILE 64
#define GTK 16
#define GPAD 4

__global__ __launch_bounds__(256) void gemm_nt(
    const float* __restrict__ A, const float* __restrict__ Bt,
    float* __restrict__ C, int M, int N, int K, int accumulate) {
  __shared__ float As[GTK][GTILE + GPAD];
  __shared__ float Bs[GTK][GTILE + GPAD];

  const int tid = threadIdx.x;
  const int m0 = blockIdx.y * GTILE;
  const int n0 = blockIdx.x * GTILE;
  const int tx = tid & 15;
  const int ty = tid >> 4;

  const int lm = tid >> 2;
  const int lk = (tid & 3) * 4;

  const float* Arow = A + (size_t)(m0 + lm) * K + lk;
  const float* Brow = Bt + (size_t)(n0 + lm) * K + lk;

  float acc[4][4];
#pragma unroll
  for (int i = 0; i < 4; i++)
#pragma unroll
    for (int j = 0; j < 4; j++) acc[i][j] = 0.f;

  for (int k0 = 0; k0 < K; k0 += GTK) {
    float4 av = *(const float4*)(Arow + k0);
    float4 bv = *(const float4*)(Brow + k0);
    As[lk + 0][lm] = av.x; As[lk + 1][lm] = av.y;
    As[lk + 2][lm] = av.z; As[lk + 3][lm] = av.w;
    Bs[lk + 0][lm] = bv.x; Bs[lk + 1][lm] = bv.y;
    Bs[lk + 2][lm] = bv.z; Bs[lk + 3][lm] = bv.w;
    __syncthreads();
#pragma unroll
    for (int kk = 0; kk < GTK; kk++) {
      float4 a4 = *(const float4*)(&As[kk][ty * 4]);
      float4 b4 = *(const float4*)(&Bs[kk][tx * 4]);
      float a[4] = {a4.x, a4.y, a4.z, a4.w};
      float b[4] = {b4.x, b4.y, b4.z, b4.w};
#pragma unroll
      for (int i = 0; i < 4; i++)
#pragma unroll
        for (int j = 0; j < 4; j++) acc[i][j] += a[i] * b[j];
    }
    __syncthreads();
  }

#pragma unroll
  for (int i = 0; i < 4; i++) {
    float* cp = C + (size_t)(m0 + ty * 4 + i) * N + n0 + tx * 4;
    float4 v = make_float4(acc[i][0], acc[i][1], acc[i][2], acc[i][3]);
    if (accumulate) {
      float4 old = *(const float4*)cp;
      v.x += old.x; v.y += old.y; v.z += old.z; v.w += old.w;
    }
    *(float4*)cp = v;
  }
}

// ---------------------------------------------------------------------------
// Flash attention, fp32, block-tiled.
// One 256-thread block per (b, h, 64-row q-tile). Iterates 64-key tiles:
//   stage K,V in LDS (coalesced) -> QK^T as 64x64x48 register-tiled GEMM
//   -> ALiBi bias + online softmax (shfl row-reduce over 16 lanes/q-group)
//   -> P via swizzled LDS transpose -> PV as 64x64x64 register-tiled GEMM.
// Thread (tq,tk): tq=tid>>4 owns q rows tq*4..+3; tk=tid&15 owns key cols /
// d cols tk*4..+3. LDS = 56 KB -> 2 blocks/CU.
// ---------------------------------------------------------------------------
#define QT 64
#define KT 64

__global__ __launch_bounds__(256) void attn_flash(
    const float* __restrict__ qkv, const float* __restrict__ log_slopes,
    float* __restrict__ obuf) {
  __shared__ float Qs[HD][QT];   // [d][q], pre-scaled by 1/sqrt(HD)
  __shared__ float Ks[HD][KT];   // [d][k]
  __shared__ float Vs[KT][64];   // [k][d] (cols 48..63 never written, discarded)
  __shared__ float Pt[KT][64];   // [k][q], column-swizzled by (q + 4k) & 63

  const int tid = threadIdx.x;
  const int qb = blockIdx.x * QT;
  const int h = blockIdx.y;
  const int b = blockIdx.z;
  const int tq = tid >> 4;   // 0..15
  const int tk = tid & 15;   // 0..15

  const float scale = 0.14433756729740643f;  // 1/sqrt(48)
  const float slope = __expf(log_slopes[h]);

  // stage Q tile, transposed + scaled: 64 rows x 12 float4
#pragma unroll
  for (int it = tid; it < QT * 12; it += 256) {
    int r = it / 12, c = it % 12;
    const float4 v = *(const float4*)(qkv + ((size_t)(b * SEQ + qb + r)) * (3 * DMODEL) + h * HD + c * 4);
    Qs[c * 4 + 0][r] = v.x * scale;
    Qs[c * 4 + 1][r] = v.y * scale;
    Qs[c * 4 + 2][r] = v.z * scale;
    Qs[c * 4 + 3][r] = v.w * scale;
  }

  float m[4], l[4], O[4][4];
#pragma unroll
  for (int i = 0; i < 4; i++) {
    m[i] = -1e30f; l[i] = 0.f;
#pragma unroll
    for (int j = 0; j < 4; j++) O[i][j] = 0.f;
  }

  for (int kb = 0; kb < SEQ; kb += KT) {
    __syncthreads();  // prev PV done: safe to overwrite Ks/Vs/Pt (covers Q stage too, 1st iter)
    // stage K (transposed) and V (row-major)
#pragma unroll
    for (int it = tid; it < KT * 12; it += 256) {
      int r = it / 12, c = it % 12;
      const size_t base = ((size_t)(b * SEQ + kb + r)) * (3 * DMODEL) + h * HD;
      const float4 kv = *(const float4*)(qkv + base + DMODEL + c * 4);
      Ks[c * 4 + 0][r] = kv.x;
      Ks[c * 4 + 1][r] = kv.y;
      Ks[c * 4 + 2][r] = kv.z;
      Ks[c * 4 + 3][r] = kv.w;
      const float4 vv = *(const float4*)(qkv + base + 2 * DMODEL + c * 4);
      *(float4*)&Vs[r][c * 4] = vv;
    }
    __syncthreads();

    // QK^T: 64x64x48 GEMM, 4x4 micro-tile
    float acc[4][4];
#pragma unroll
    for (int i = 0; i < 4; i++)
#pragma unroll
      for (int j = 0; j < 4; j++) acc[i][j] = 0.f;
#pragma unroll
    for (int d = 0; d < HD; d++) {
      float4 q4 = *(const float4*)&Qs[d][tq * 4];
      float4 k4 = *(const float4*)&Ks[d][tk * 4];
      float qa[4] = {q4.x, q4.y, q4.z, q4.w};
      float ka[4] = {k4.x, k4.y, k4.z, k4.w};
#pragma unroll
      for (int i = 0; i < 4; i++)
#pragma unroll
        for (int j = 0; j < 4; j++) acc[i][j] += qa[i] * ka[j];
    }

    // ALiBi bias + online softmax
    float rmax[4], rsum[4];
#pragma unroll
    for (int qi = 0; qi < 4; qi++) {
      const int qg = qb + tq * 4 + qi;
#pragma unroll
      for (int ki = 0; ki < 4; ki++) {
        const int kg = kb + tk * 4 + ki;
        acc[qi][ki] -= slope * fabsf((float)(qg - kg));
      }
      float r = fmaxf(fmaxf(acc[qi][0], acc[qi][1]), fmaxf(acc[qi][2], acc[qi][3]));
#pragma unroll
      for (int off = 1; off < 16; off <<= 1) r = fmaxf(r, __shfl_xor(r, off, 64));
      rmax[qi] = r;
    }
#pragma unroll
    for (int qi = 0; qi < 4; qi++) {
      const float mnew = fmaxf(m[qi], rmax[qi]);
      const float corr = __expf(m[qi] - mnew);
      float rs = 0.f;
#pragma unroll
      for (int ki = 0; ki < 4; ki++) {
        acc[qi][ki] = __expf(acc[qi][ki] - mnew);
        rs += acc[qi][ki];
      }
#pragma unroll
      for (int off = 1; off < 16; off <<= 1) rs += __shfl_xor(rs, off, 64);
      l[qi] = l[qi] * corr + rs;
      m[qi] = mnew;
#pragma unroll
      for (int j = 0; j < 4; j++) O[qi][j] *= corr;
    }

    // write P transposed (swizzled cols): Pt[k][(q0 + 4k) & 63] = {P[q0..q3][k]}
#pragma unroll
    for (int ki = 0; ki < 4; ki++) {
      const int k = tk * 4 + ki;
      const int col = (tq * 4 + 4 * k) & 63;
      *(float4*)&Pt[k][col] = make_float4(acc[0][ki], acc[1][ki], acc[2][ki], acc[3][ki]);
    }
    __syncthreads();

    // PV: 64x64x64 GEMM (d padded to 64; tk>=12 lanes do discarded work)
#pragma unroll
    for (int k = 0; k < KT; k++) {
      const float4 p4 = *(const float4*)&Pt[k][(tq * 4 + 4 * k) & 63];
      const float4 v4 = *(const float4*)&Vs[k][tk * 4];
      float pa[4] = {p4.x, p4.y, p4.z, p4.w};
      float va[4] = {v4.x, v4.y, v4.z, v4.w};
#pragma unroll
      for (int i = 0; i < 4; i++)
#pragma unroll
        for (int j = 0; j < 4; j++) O[i][j] += pa[i] * va[j];
    }
  }

  // epilogue: O / l -> obuf
  if (tk < 12) {
#pragma unroll
    for (int qi = 0; qi < 4; qi++) {
      const float inv = 1.0f / l[qi];
      float* op = obuf + ((size_t)(b * SEQ + qb + tq * 4 + qi)) * DMODEL + h * HD + tk * 4;
      *(float4*)op = make_float4(O[qi][0] * inv, O[qi][1] * inv, O[qi][2] * inv, O[qi][3] * inv);
    }
  }
}

// ---------------------------------------------------------------------------
// g = silu(g) * u
// ---------------------------------------------------------------------------
__global__ __launch_bounds__(256) void silu_mul_kernel(
    float* __restrict__ g, const float* __restrict__ u, size_t n) {
  size_t i = (size_t)blockIdx.x * blockDim.x + threadIdx.x;
  size_t stride = (size_t)gridDim.x * blockDim.x;
  for (; i < n; i += stride) {
    float gv = g[i];
    float sig = 1.0f / (1.0f + __expf(-gv));
    g[i] = gv * sig * u[i];
  }
}

// ---------------------------------------------------------------------------
// launcher
// ---------------------------------------------------------------------------
extern "C" void kernel_launch(void* const* d_in, const int* in_sizes, int n_in,
                              void* d_out, int out_size, void* d_ws, size_t ws_size,
                              hipStream_t stream) {
  const float* cls_tokens = (const float*)d_in[0];
  const float* cls_token  = (const float*)d_in[1];
  const float* log_slopes = (const float*)d_in[2];
  const float* Wqkv = (const float*)d_in[3];
  const float* Wo   = (const float*)d_in[4];
  const float* Wg   = (const float*)d_in[5];
  const float* Wu   = (const float*)d_in[6];
  const float* Wd   = (const float*)d_in[7];
  const float* ln1_w = (const float*)d_in[8];
  const float* ln1_b = (const float*)d_in[9];
  const float* ln2_w = (const float*)d_in[10];
  const float* ln2_b = (const float*)d_in[11];
  const float* fin_w = (const float*)d_in[12];
  const float* fin_b = (const float*)d_in[13];
  float* out = (float*)d_out;

  float* ws = (float*)d_ws;
  const size_t ROWS = (size_t)BATCH * SEQ;           // 4096
  float* x   = ws;                                   // 3,145,728
  float* h   = ws + (size_t)3145728;                 // 3,145,728
  float* qkv = ws + (size_t)6291456;                 // 9,437,184
  float* o   = ws + (size_t)15728640;                // 3,145,728
  float* g   = ws + (size_t)18874368;                // 12,582,912
  float* u   = ws + (size_t)6291456;                 // aliases qkv+o (dead by then)

  // build x
  {
    const size_t total = ROWS * DMODEL;
    int blocks = (int)((total + 255) / 256);
    concat_kernel<<<blocks, 256, 0, stream>>>(cls_tokens, cls_token, x);
  }

  for (int l = 0; l < LNUM; l++) {
    const float* wqkv_l = Wqkv + (size_t)l * 3 * DMODEL * DMODEL;
    const float* wo_l   = Wo + (size_t)l * DMODEL * DMODEL;
    const float* wg_l   = Wg + (size_t)l * FFDIM * DMODEL;
    const float* wu_l   = Wu + (size_t)l * FFDIM * DMODEL;
    const float* wd_l   = Wd + (size_t)l * DMODEL * FFDIM;

    // h = LN1(x)
    ln_kernel<<<(int)ROWS, 256, 0, stream>>>(x, h, ln1_w + l * DMODEL,
                                             ln1_b + l * DMODEL, DMODEL, DMODEL);
    // qkv = h @ Wqkv^T
    gemm_nt<<<dim3(3 * DMODEL / GTILE, ROWS / GTILE), 256, 0, stream>>>(
        h, wqkv_l, qkv, (int)ROWS, 3 * DMODEL, DMODEL, 0);
    // attention (flash, block-tiled)
    attn_flash<<<dim3(SEQ / QT, HNUM, BATCH), 256, 0, stream>>>(qkv, log_slopes, o);
    // x += o @ Wo^T
    gemm_nt<<<dim3(DMODEL / GTILE, ROWS / GTILE), 256, 0, stream>>>(
        o, wo_l, x, (int)ROWS, DMODEL, DMODEL, 1);
    // h = LN2(x)
    ln_kernel<<<(int)ROWS, 256, 0, stream>>>(x, h, ln2_w + l * DMODEL,
                                             ln2_b + l * DMODEL, DMODEL, DMODEL);
    // g = h @ Wg^T ; u = h @ Wu^T
    gemm_nt<<<dim3(FFDIM / GTILE, ROWS / GTILE), 256, 0, stream>>>(
        h, wg_l, g, (int)ROWS, FFDIM, DMODEL, 0);
    gemm_nt<<<dim3(FFDIM / GTILE, ROWS / GTILE), 256, 0, stream>>>(
        h, wu_l, u, (int)ROWS, FFDIM, DMODEL, 0);
    // g = silu(g) * u
    silu_mul_kernel<<<4096, 256, 0, stream>>>(g, u, ROWS * FFDIM);
    // x += g @ Wd^T
    gemm_nt<<<dim3(DMODEL / GTILE, ROWS / GTILE), 256, 0, stream>>>(
        g, wd_l, x, (int)ROWS, DMODEL, FFDIM, 1);
  }

  // out = LN(x[:, 0, :])
  ln_kernel<<<BATCH, 256, 0, stream>>>(x, out, fin_w, fin_b,
                                       (size_t)SEQ * DMODEL, DMODEL);
}

// Round 3
// 3239.836 us; speedup vs baseline: 8.6093x; 2.5819x over previous
//
#include <hip/hip_runtime.h>
#include <hip/hip_bf16.h>

// Problem constants
#define LNUM 6
#define HNUM 16
#define DMODEL 768
#define FFDIM 3072
#define BATCH 4
#define NTOK 1023
#define SEQ 1024          // NTOK + 1
#define HD 48             // DMODEL / HNUM
#define EPS 1e-5f

typedef __hip_bfloat16 bf16;

__device__ __forceinline__ unsigned short f2bf_raw(float f) {
  bf16 h = __float2bfloat16(f);
  union { bf16 h; unsigned short s; } u; u.h = h; return u.s;
}
__device__ __forceinline__ float bflo(unsigned int u) { return __uint_as_float(u << 16); }
__device__ __forceinline__ float bfhi(unsigned int u) { return __uint_as_float(u & 0xffff0000u); }

// ---------------------------------------------------------------------------
// concat: x[b,s,:] = s==0 ? cls_token : cls_tokens[b,s-1,:]  (fp32 residual)
// ---------------------------------------------------------------------------
__global__ __launch_bounds__(256) void concat_kernel(
    const float* __restrict__ cls_tokens, const float* __restrict__ cls_token,
    float* __restrict__ x) {
  size_t i = (size_t)blockIdx.x * blockDim.x + threadIdx.x;
  const size_t total = (size_t)BATCH * SEQ * DMODEL;
  if (i >= total) return;
  int d = (int)(i % DMODEL);
  size_t bs = i / DMODEL;
  int s = (int)(bs % SEQ);
  int b = (int)(bs / SEQ);
  float v;
  if (s == 0) v = cls_token[d];
  else v = cls_tokens[((size_t)b * NTOK + (s - 1)) * DMODEL + d];
  x[i] = v;
}

// ---------------------------------------------------------------------------
// per-layer weight pack fp32 -> bf16 (Wqkv | Wo | Wg | Wu | Wd concatenated)
// total 9,437,184 elements = 2,359,296 float4s; grid exactly 9216 x 256
// ---------------------------------------------------------------------------
#define W_QKV4  442368
#define W_O4    147456
#define W_FF4   589824
__global__ __launch_bounds__(256) void convert_w_kernel(
    const float* __restrict__ wqkv, const float* __restrict__ wo,
    const float* __restrict__ wg, const float* __restrict__ wu,
    const float* __restrict__ wd, bf16* __restrict__ dst) {
  size_t i4 = (size_t)blockIdx.x * 256 + threadIdx.x;
  size_t off4 = i4;
  const float* src;
  if (off4 < W_QKV4) src = wqkv;
  else { off4 -= W_QKV4;
    if (off4 < W_O4) src = wo;
    else { off4 -= W_O4;
      if (off4 < W_FF4) src = wg;
      else { off4 -= W_FF4;
        if (off4 < W_FF4) src = wu;
        else { off4 -= W_FF4; src = wd; } } } }
  float4 v = ((const float4*)src)[off4];
  ushort4 o;
  o.x = f2bf_raw(v.x); o.y = f2bf_raw(v.y);
  o.z = f2bf_raw(v.z); o.w = f2bf_raw(v.w);
  ((ushort4*)dst)[i4] = o;
}

// ---------------------------------------------------------------------------
// layernorm: one 256-thread block per row of 768. OUT = float or bf16.
// ---------------------------------------------------------------------------
__device__ __forceinline__ void st_ln(float* p, float v) { *p = v; }
__device__ __forceinline__ void st_ln(bf16* p, float v) { *p = __float2bfloat16(v); }

template <typename OUT>
__global__ __launch_bounds__(256) void ln_kernel(
    const float* __restrict__ in, OUT* __restrict__ out,
    const float* __restrict__ w, const float* __restrict__ bias,
    size_t in_stride, size_t out_stride) {
  const int row = blockIdx.x;
  const int tid = threadIdx.x;
  const float* x = in + (size_t)row * in_stride;
  OUT* y = out + (size_t)row * out_stride;

  float v0 = x[tid], v1 = x[tid + 256], v2 = x[tid + 512];
  float s = v0 + v1 + v2;
  float sq = v0 * v0 + v1 * v1 + v2 * v2;

  __shared__ float s_sum[256];
  __shared__ float s_sq[256];
  s_sum[tid] = s;
  s_sq[tid] = sq;
  __syncthreads();
  for (int off = 128; off > 0; off >>= 1) {
    if (tid < off) {
      s_sum[tid] += s_sum[tid + off];
      s_sq[tid] += s_sq[tid + off];
    }
    __syncthreads();
  }
  const float inv_d = 1.0f / (float)DMODEL;
  float mean = s_sum[0] * inv_d;
  float var = s_sq[0] * inv_d - mean * mean;
  float rstd = rsqrtf(var + EPS);

  st_ln(y + tid,       (v0 - mean) * rstd * w[tid]       + bias[tid]);
  st_ln(y + tid + 256, (v1 - mean) * rstd * w[tid + 256] + bias[tid + 256]);
  st_ln(y + tid + 512, (v2 - mean) * rstd * w[tid + 512] + bias[tid + 512]);
}

// ---------------------------------------------------------------------------
// bf16 MFMA NT GEMM (m97 structure): C[m,n] = sum_k A[m,k]*B[n,k]
// A: M x K bf16 row-major, B: N x K bf16 row-major. 128x128 tile, BK=32.
// 256 threads = 4 waves in 2x2; wave does 4x4 grid of 16x16x32 MFMA.
// Staging via global_load_lds width=16 (wave-uniform LDS base + lane*16).
// CMODE: 0 = store fp32, 1 = accumulate fp32, 2 = store bf16.
// ---------------------------------------------------------------------------
#define BM 128
#define BN 128
#define BK 32

typedef __attribute__((ext_vector_type(8))) short bfrag;
typedef __attribute__((ext_vector_type(4))) float f32x4;

__device__ __forceinline__ void async_copy16(const void* g, void* l) {
  __builtin_amdgcn_global_load_lds(
      (const __attribute__((address_space(1))) void*)g,
      (__attribute__((address_space(3))) void*)l, 16, 0, 0);
}

template <int CMODE>
__global__ __launch_bounds__(256) void gemm_bf16(
    const bf16* __restrict__ A, const bf16* __restrict__ B,
    void* __restrict__ Cv, int M, int N, int K) {
  __shared__ bf16 As[BM][BK];  // 8 KB, row-major, 64 B rows
  __shared__ bf16 Bs[BN][BK];  // 8 KB

  const int tid = threadIdx.x;
  const int wave = tid >> 6;
  const int lane = tid & 63;
  const int m0 = blockIdx.y * BM;
  const int n0 = blockIdx.x * BN;
  const int wm = (wave & 1) * 64;
  const int wn = (wave >> 1) * 64;

  f32x4 acc[4][4];
#pragma unroll
  for (int i = 0; i < 4; i++)
#pragma unroll
    for (int j = 0; j < 4; j++) acc[i][j] = (f32x4)(0.f);

  // staging: chunk c = j*4 + wave covers rows c*16..c*16+15 (1 KB per instr)
  const int lrow = lane >> 2;       // 0..15
  const int lcol = (lane & 3) * 8;  // 0,8,16,24
  const bf16* Ag[2]; const bf16* Bg[2];
  void *AsB[2], *BsB[2];
#pragma unroll
  for (int j = 0; j < 2; j++) {
    int c = j * 4 + wave;
    Ag[j] = A + (size_t)(m0 + c * 16 + lrow) * K + lcol;
    Bg[j] = B + (size_t)(n0 + c * 16 + lrow) * K + lcol;
    AsB[j] = (void*)&As[c * 16][0];
    BsB[j] = (void*)&Bs[c * 16][0];
  }

  const int fr = lane & 15;         // row within 16x16 frag
  const int fk = (lane >> 4) * 8;   // k offset within BK

  for (int k0 = 0; k0 < K; k0 += BK) {
    async_copy16(Ag[0] + k0, AsB[0]);
    async_copy16(Ag[1] + k0, AsB[1]);
    async_copy16(Bg[0] + k0, BsB[0]);
    async_copy16(Bg[1] + k0, BsB[1]);
    __syncthreads();

    bfrag a[4], b[4];
#pragma unroll
    for (int i = 0; i < 4; i++) {
      a[i] = *(const bfrag*)&As[wm + i * 16 + fr][fk];
      b[i] = *(const bfrag*)&Bs[wn + i * 16 + fr][fk];
    }
#pragma unroll
    for (int i = 0; i < 4; i++)
#pragma unroll
      for (int j = 0; j < 4; j++)
        acc[i][j] = __builtin_amdgcn_mfma_f32_16x16x32_bf16(a[i], b[j], acc[i][j], 0, 0, 0);
    __syncthreads();
  }

  // epilogue: C/D layout col=lane&15, row=(lane>>4)*4+reg
  const int ccol = lane & 15;
  const int crow = (lane >> 4) * 4;
#pragma unroll
  for (int i = 0; i < 4; i++) {
#pragma unroll
    for (int j = 0; j < 4; j++) {
#pragma unroll
      for (int r = 0; r < 4; r++) {
        const size_t gm = m0 + wm + i * 16 + crow + r;
        const size_t gn = n0 + wn + j * 16 + ccol;
        if (CMODE == 2) {
          ((bf16*)Cv)[gm * N + gn] = __float2bfloat16(acc[i][j][r]);
        } else if (CMODE == 1) {
          float* cp = (float*)Cv + gm * N + gn;
          *cp += acc[i][j][r];
        } else {
          ((float*)Cv)[gm * N + gn] = acc[i][j][r];
        }
      }
    }
  }
}

// ---------------------------------------------------------------------------
// Flash attention, fp32 compute, bf16 qkv in / bf16 o out.
// One 256-thread block per (b, h, 64-row q-tile).
// ---------------------------------------------------------------------------
#define QT 64
#define KT 64

__global__ __launch_bounds__(256) void attn_flash(
    const bf16* __restrict__ qkv, const float* __restrict__ log_slopes,
    bf16* __restrict__ obuf) {
  __shared__ float Qs[HD][QT];   // [d][q], pre-scaled
  __shared__ float Ks[HD][KT];   // [d][k]
  __shared__ float Vs[KT][64];   // [k][d] (cols 48..63 garbage, discarded)
  __shared__ float Pt[KT][64];   // [k][q], column-swizzled by (q + 4k) & 63

  const int tid = threadIdx.x;
  const int qb = blockIdx.x * QT;
  const int h = blockIdx.y;
  const int b = blockIdx.z;
  const int tq = tid >> 4;
  const int tk = tid & 15;

  const float scale = 0.14433756729740643f;  // 1/sqrt(48)
  const float slope = __expf(log_slopes[h]);

  // stage Q tile transposed + scaled: 64 rows x 6 chunks of 8 bf16
  for (int it = tid; it < QT * 6; it += 256) {
    int r = it / 6, c = it % 6;
    const uint4 raw = *(const uint4*)(qkv + ((size_t)(b * SEQ + qb + r)) * (3 * DMODEL) + h * HD + c * 8);
    Qs[c * 8 + 0][r] = bflo(raw.x) * scale;
    Qs[c * 8 + 1][r] = bfhi(raw.x) * scale;
    Qs[c * 8 + 2][r] = bflo(raw.y) * scale;
    Qs[c * 8 + 3][r] = bfhi(raw.y) * scale;
    Qs[c * 8 + 4][r] = bflo(raw.z) * scale;
    Qs[c * 8 + 5][r] = bfhi(raw.z) * scale;
    Qs[c * 8 + 6][r] = bflo(raw.w) * scale;
    Qs[c * 8 + 7][r] = bfhi(raw.w) * scale;
  }

  float m[4], l[4], O[4][4];
#pragma unroll
  for (int i = 0; i < 4; i++) {
    m[i] = -1e30f; l[i] = 0.f;
#pragma unroll
    for (int j = 0; j < 4; j++) O[i][j] = 0.f;
  }

  for (int kb = 0; kb < SEQ; kb += KT) {
    __syncthreads();  // prev PV done (covers Q stage on 1st iter)
    for (int it = tid; it < KT * 6; it += 256) {
      int r = it / 6, c = it % 6;
      const bf16* base = qkv + ((size_t)(b * SEQ + kb + r)) * (3 * DMODEL) + h * HD;
      const uint4 kraw = *(const uint4*)(base + DMODEL + c * 8);
      Ks[c * 8 + 0][r] = bflo(kraw.x);
      Ks[c * 8 + 1][r] = bfhi(kraw.x);
      Ks[c * 8 + 2][r] = bflo(kraw.y);
      Ks[c * 8 + 3][r] = bfhi(kraw.y);
      Ks[c * 8 + 4][r] = bflo(kraw.z);
      Ks[c * 8 + 5][r] = bfhi(kraw.z);
      Ks[c * 8 + 6][r] = bflo(kraw.w);
      Ks[c * 8 + 7][r] = bfhi(kraw.w);
      const uint4 vraw = *(const uint4*)(base + 2 * DMODEL + c * 8);
      float* vp = &Vs[r][c * 8];
      vp[0] = bflo(vraw.x); vp[1] = bfhi(vraw.x);
      vp[2] = bflo(vraw.y); vp[3] = bfhi(vraw.y);
      vp[4] = bflo(vraw.z); vp[5] = bfhi(vraw.z);
      vp[6] = bflo(vraw.w); vp[7] = bfhi(vraw.w);
    }
    __syncthreads();

    // QK^T: 64x64x48, 4x4 micro-tile
    float acc[4][4];
#pragma unroll
    for (int i = 0; i < 4; i++)
#pragma unroll
      for (int j = 0; j < 4; j++) acc[i][j] = 0.f;
#pragma unroll
    for (int d = 0; d < HD; d++) {
      float4 q4 = *(const float4*)&Qs[d][tq * 4];
      float4 k4 = *(const float4*)&Ks[d][tk * 4];
      float qa[4] = {q4.x, q4.y, q4.z, q4.w};
      float ka[4] = {k4.x, k4.y, k4.z, k4.w};
#pragma unroll
      for (int i = 0; i < 4; i++)
#pragma unroll
        for (int j = 0; j < 4; j++) acc[i][j] += qa[i] * ka[j];
    }

    // ALiBi bias + online softmax
    float rmax[4];
#pragma unroll
    for (int qi = 0; qi < 4; qi++) {
      const int qg = qb + tq * 4 + qi;
#pragma unroll
      for (int ki = 0; ki < 4; ki++) {
        const int kg = kb + tk * 4 + ki;
        acc[qi][ki] -= slope * fabsf((float)(qg - kg));
      }
      float r = fmaxf(fmaxf(acc[qi][0], acc[qi][1]), fmaxf(acc[qi][2], acc[qi][3]));
#pragma unroll
      for (int off = 1; off < 16; off <<= 1) r = fmaxf(r, __shfl_xor(r, off, 64));
      rmax[qi] = r;
    }
#pragma unroll
    for (int qi = 0; qi < 4; qi++) {
      const float mnew = fmaxf(m[qi], rmax[qi]);
      const float corr = __expf(m[qi] - mnew);
      float rs = 0.f;
#pragma unroll
      for (int ki = 0; ki < 4; ki++) {
        acc[qi][ki] = __expf(acc[qi][ki] - mnew);
        rs += acc[qi][ki];
      }
#pragma unroll
      for (int off = 1; off < 16; off <<= 1) rs += __shfl_xor(rs, off, 64);
      l[qi] = l[qi] * corr + rs;
      m[qi] = mnew;
#pragma unroll
      for (int j = 0; j < 4; j++) O[qi][j] *= corr;
    }

    // P transposed (swizzled cols)
#pragma unroll
    for (int ki = 0; ki < 4; ki++) {
      const int k = tk * 4 + ki;
      const int col = (tq * 4 + 4 * k) & 63;
      *(float4*)&Pt[k][col] = make_float4(acc[0][ki], acc[1][ki], acc[2][ki], acc[3][ki]);
    }
    __syncthreads();

    // PV: 64x64x64
#pragma unroll
    for (int k = 0; k < KT; k++) {
      const float4 p4 = *(const float4*)&Pt[k][(tq * 4 + 4 * k) & 63];
      const float4 v4 = *(const float4*)&Vs[k][tk * 4];
      float pa[4] = {p4.x, p4.y, p4.z, p4.w};
      float va[4] = {v4.x, v4.y, v4.z, v4.w};
#pragma unroll
      for (int i = 0; i < 4; i++)
#pragma unroll
        for (int j = 0; j < 4; j++) O[i][j] += pa[i] * va[j];
    }
  }

  // epilogue -> bf16 o
  if (tk < 12) {
#pragma unroll
    for (int qi = 0; qi < 4; qi++) {
      const float inv = 1.0f / l[qi];
      bf16* op = obuf + ((size_t)(b * SEQ + qb + tq * 4 + qi)) * DMODEL + h * HD + tk * 4;
      op[0] = __float2bfloat16(O[qi][0] * inv);
      op[1] = __float2bfloat16(O[qi][1] * inv);
      op[2] = __float2bfloat16(O[qi][2] * inv);
      op[3] = __float2bfloat16(O[qi][3] * inv);
    }
  }
}

// ---------------------------------------------------------------------------
// gu = silu(g) * u, bf16 in/out, processed as packed pairs
// ---------------------------------------------------------------------------
__global__ __launch_bounds__(256) void silu_mul_kernel(
    bf16* __restrict__ g, const bf16* __restrict__ u, size_t n2) {
  size_t i = (size_t)blockIdx.x * blockDim.x + threadIdx.x;
  size_t stride = (size_t)gridDim.x * blockDim.x;
  unsigned int* gp = (unsigned int*)g;
  const unsigned int* up = (const unsigned int*)u;
  for (; i < n2; i += stride) {
    unsigned int gu_ = gp[i], uu = up[i];
    float g0 = bflo(gu_), g1 = bfhi(gu_);
    float u0 = bflo(uu), u1 = bfhi(uu);
    float r0 = g0 / (1.0f + __expf(-g0)) * u0;
    float r1 = g1 / (1.0f + __expf(-g1)) * u1;
    gp[i] = (unsigned int)f2bf_raw(r0) | ((unsigned int)f2bf_raw(r1) << 16);
  }
}

// ---------------------------------------------------------------------------
// launcher
// ---------------------------------------------------------------------------
extern "C" void kernel_launch(void* const* d_in, const int* in_sizes, int n_in,
                              void* d_out, int out_size, void* d_ws, size_t ws_size,
                              hipStream_t stream) {
  const float* cls_tokens = (const float*)d_in[0];
  const float* cls_token  = (const float*)d_in[1];
  const float* log_slopes = (const float*)d_in[2];
  const float* Wqkv = (const float*)d_in[3];
  const float* Wo   = (const float*)d_in[4];
  const float* Wg   = (const float*)d_in[5];
  const float* Wu   = (const float*)d_in[6];
  const float* Wd   = (const float*)d_in[7];
  const float* ln1_w = (const float*)d_in[8];
  const float* ln1_b = (const float*)d_in[9];
  const float* ln2_w = (const float*)d_in[10];
  const float* ln2_b = (const float*)d_in[11];
  const float* fin_w = (const float*)d_in[12];
  const float* fin_b = (const float*)d_in[13];
  float* out = (float*)d_out;

  const size_t ROWS = (size_t)BATCH * SEQ;  // 4096
  char* wsb = (char*)d_ws;
  // byte offsets (total ~113.2 MB)
  float* x    = (float*)(wsb);                       // 12,582,912 B
  bf16* qkvb  = (bf16*)(wsb + 12582912);             // 18,874,368 B
  bf16* hb    = (bf16*)(wsb + 31457280);             //  6,291,456 B
  bf16* ob    = (bf16*)(wsb + 37748736);             //  6,291,456 B
  bf16* gb    = (bf16*)(wsb + 44040192);             // 25,165,824 B
  bf16* ub    = (bf16*)(wsb + 69206016);             // 25,165,824 B
  bf16* wbf   = (bf16*)(wsb + 94371840);             // 18,874,368 B -> end 113,246,208

  // per-layer bf16 weight views inside wbf
  bf16* wqkv_b = wbf;                   // 1,769,472 el
  bf16* wo_b   = wbf + 1769472;         //   589,824 el
  bf16* wg_b   = wbf + 2359296;         // 2,359,296 el
  bf16* wu_b   = wbf + 4718592;         // 2,359,296 el
  bf16* wd_b   = wbf + 7077888;         // 2,359,296 el

  // build x
  {
    const size_t total = ROWS * DMODEL;
    concat_kernel<<<(int)((total + 255) / 256), 256, 0, stream>>>(cls_tokens, cls_token, x);
  }

  for (int l = 0; l < LNUM; l++) {
    // convert this layer's weights to bf16
    convert_w_kernel<<<9216, 256, 0, stream>>>(
        Wqkv + (size_t)l * 3 * DMODEL * DMODEL, Wo + (size_t)l * DMODEL * DMODEL,
        Wg + (size_t)l * FFDIM * DMODEL, Wu + (size_t)l * FFDIM * DMODEL,
        Wd + (size_t)l * DMODEL * FFDIM, wbf);

    // h = LN1(x) -> bf16
    ln_kernel<bf16><<<(int)ROWS, 256, 0, stream>>>(
        x, hb, ln1_w + l * DMODEL, ln1_b + l * DMODEL, DMODEL, DMODEL);
    // qkv = h @ Wqkv^T -> bf16
    gemm_bf16<2><<<dim3(3 * DMODEL / BN, ROWS / BM), 256, 0, stream>>>(
        hb, wqkv_b, qkvb, (int)ROWS, 3 * DMODEL, DMODEL);
    // attention
    attn_flash<<<dim3(SEQ / QT, HNUM, BATCH), 256, 0, stream>>>(qkvb, log_slopes, ob);
    // x += o @ Wo^T
    gemm_bf16<1><<<dim3(DMODEL / BN, ROWS / BM), 256, 0, stream>>>(
        ob, wo_b, x, (int)ROWS, DMODEL, DMODEL);
    // h = LN2(x) -> bf16
    ln_kernel<bf16><<<(int)ROWS, 256, 0, stream>>>(
        x, hb, ln2_w + l * DMODEL, ln2_b + l * DMODEL, DMODEL, DMODEL);
    // g = h @ Wg^T ; u = h @ Wu^T  (bf16 out)
    gemm_bf16<2><<<dim3(FFDIM / BN, ROWS / BM), 256, 0, stream>>>(
        hb, wg_b, gb, (int)ROWS, FFDIM, DMODEL);
    gemm_bf16<2><<<dim3(FFDIM / BN, ROWS / BM), 256, 0, stream>>>(
        hb, wu_b, ub, (int)ROWS, FFDIM, DMODEL);
    // g = silu(g) * u
    silu_mul_kernel<<<4096, 256, 0, stream>>>(gb, ub, ROWS * FFDIM / 2);
    // x += g @ Wd^T
    gemm_bf16<1><<<dim3(DMODEL / BN, ROWS / BM), 256, 0, stream>>>(
        gb, wd_b, x, (int)ROWS, DMODEL, FFDIM);
  }

  // out = LN(x[:, 0, :]) fp32
  ln_kernel<float><<<BATCH, 256, 0, stream>>>(x, out, fin_w, fin_b,
                                              (size_t)SEQ * DMODEL, DMODEL);
}

// Round 4
// 2051.141 us; speedup vs baseline: 13.5986x; 1.5795x over previous
//
#include <hip/hip_runtime.h>
#include <hip/hip_bf16.h>

// Problem constants
#define LNUM 6
#define HNUM 16
#define DMODEL 768
#define FFDIM 3072
#define BATCH 4
#define NTOK 1023
#define SEQ 1024          // NTOK + 1
#define HD 48             // DMODEL / HNUM
#define EPS 1e-5f

typedef __hip_bfloat16 bf16;

__device__ __forceinline__ unsigned short f2bf_raw(float f) {
  bf16 h = __float2bfloat16(f);
  union { bf16 h; unsigned short s; } u; u.h = h; return u.s;
}
__device__ __forceinline__ float bflo(unsigned int u) { return __uint_as_float(u << 16); }
__device__ __forceinline__ float bfhi(unsigned int u) { return __uint_as_float(u & 0xffff0000u); }

// ---------------------------------------------------------------------------
// concat: x[b,s,:] = s==0 ? cls_token : cls_tokens[b,s-1,:]  (fp32 residual)
// ---------------------------------------------------------------------------
__global__ __launch_bounds__(256) void concat_kernel(
    const float* __restrict__ cls_tokens, const float* __restrict__ cls_token,
    float* __restrict__ x) {
  size_t i = (size_t)blockIdx.x * blockDim.x + threadIdx.x;
  const size_t total = (size_t)BATCH * SEQ * DMODEL;
  if (i >= total) return;
  int d = (int)(i % DMODEL);
  size_t bs = i / DMODEL;
  int s = (int)(bs % SEQ);
  int b = (int)(bs / SEQ);
  float v;
  if (s == 0) v = cls_token[d];
  else v = cls_tokens[((size_t)b * NTOK + (s - 1)) * DMODEL + d];
  x[i] = v;
}

// ---------------------------------------------------------------------------
// per-layer weight pack fp32 -> bf16 (Wqkv | Wo | Wg | Wu | Wd concatenated)
// ---------------------------------------------------------------------------
#define W_QKV4  442368
#define W_O4    147456
#define W_FF4   589824
__global__ __launch_bounds__(256) void convert_w_kernel(
    const float* __restrict__ wqkv, const float* __restrict__ wo,
    const float* __restrict__ wg, const float* __restrict__ wu,
    const float* __restrict__ wd, bf16* __restrict__ dst) {
  size_t i4 = (size_t)blockIdx.x * 256 + threadIdx.x;
  size_t off4 = i4;
  const float* src;
  if (off4 < W_QKV4) src = wqkv;
  else { off4 -= W_QKV4;
    if (off4 < W_O4) src = wo;
    else { off4 -= W_O4;
      if (off4 < W_FF4) src = wg;
      else { off4 -= W_FF4;
        if (off4 < W_FF4) src = wu;
        else { off4 -= W_FF4; src = wd; } } } }
  float4 v = ((const float4*)src)[off4];
  ushort4 o;
  o.x = f2bf_raw(v.x); o.y = f2bf_raw(v.y);
  o.z = f2bf_raw(v.z); o.w = f2bf_raw(v.w);
  ((ushort4*)dst)[i4] = o;
}

// ---------------------------------------------------------------------------
// layernorm: one 256-thread block per row of 768. OUT = float or bf16.
// ---------------------------------------------------------------------------
__device__ __forceinline__ void st_ln(float* p, float v) { *p = v; }
__device__ __forceinline__ void st_ln(bf16* p, float v) { *p = __float2bfloat16(v); }

template <typename OUT>
__global__ __launch_bounds__(256) void ln_kernel(
    const float* __restrict__ in, OUT* __restrict__ out,
    const float* __restrict__ w, const float* __restrict__ bias,
    size_t in_stride, size_t out_stride) {
  const int row = blockIdx.x;
  const int tid = threadIdx.x;
  const float* x = in + (size_t)row * in_stride;
  OUT* y = out + (size_t)row * out_stride;

  float v0 = x[tid], v1 = x[tid + 256], v2 = x[tid + 512];
  float s = v0 + v1 + v2;
  float sq = v0 * v0 + v1 * v1 + v2 * v2;

  __shared__ float s_sum[256];
  __shared__ float s_sq[256];
  s_sum[tid] = s;
  s_sq[tid] = sq;
  __syncthreads();
  for (int off = 128; off > 0; off >>= 1) {
    if (tid < off) {
      s_sum[tid] += s_sum[tid + off];
      s_sq[tid] += s_sq[tid + off];
    }
    __syncthreads();
  }
  const float inv_d = 1.0f / (float)DMODEL;
  float mean = s_sum[0] * inv_d;
  float var = s_sq[0] * inv_d - mean * mean;
  float rstd = rsqrtf(var + EPS);

  st_ln(y + tid,       (v0 - mean) * rstd * w[tid]       + bias[tid]);
  st_ln(y + tid + 256, (v1 - mean) * rstd * w[tid + 256] + bias[tid + 256]);
  st_ln(y + tid + 512, (v2 - mean) * rstd * w[tid + 512] + bias[tid + 512]);
}

// ---------------------------------------------------------------------------
// bf16 MFMA NT GEMM (m97 structure)
// ---------------------------------------------------------------------------
#define BM 128
#define BN 128
#define BK 32

typedef __attribute__((ext_vector_type(8))) short bfrag;
typedef __attribute__((ext_vector_type(4))) float f32x4;

__device__ __forceinline__ void async_copy16(const void* g, void* l) {
  __builtin_amdgcn_global_load_lds(
      (const __attribute__((address_space(1))) void*)g,
      (__attribute__((address_space(3))) void*)l, 16, 0, 0);
}

template <int CMODE>
__global__ __launch_bounds__(256) void gemm_bf16(
    const bf16* __restrict__ A, const bf16* __restrict__ B,
    void* __restrict__ Cv, int M, int N, int K) {
  __shared__ bf16 As[BM][BK];
  __shared__ bf16 Bs[BN][BK];

  const int tid = threadIdx.x;
  const int wave = tid >> 6;
  const int lane = tid & 63;
  const int m0 = blockIdx.y * BM;
  const int n0 = blockIdx.x * BN;
  const int wm = (wave & 1) * 64;
  const int wn = (wave >> 1) * 64;

  f32x4 acc[4][4];
#pragma unroll
  for (int i = 0; i < 4; i++)
#pragma unroll
    for (int j = 0; j < 4; j++) acc[i][j] = (f32x4)(0.f);

  const int lrow = lane >> 2;
  const int lcol = (lane & 3) * 8;
  const bf16* Ag[2]; const bf16* Bg[2];
  void *AsB[2], *BsB[2];
#pragma unroll
  for (int j = 0; j < 2; j++) {
    int c = j * 4 + wave;
    Ag[j] = A + (size_t)(m0 + c * 16 + lrow) * K + lcol;
    Bg[j] = B + (size_t)(n0 + c * 16 + lrow) * K + lcol;
    AsB[j] = (void*)&As[c * 16][0];
    BsB[j] = (void*)&Bs[c * 16][0];
  }

  const int fr = lane & 15;
  const int fk = (lane >> 4) * 8;

  for (int k0 = 0; k0 < K; k0 += BK) {
    async_copy16(Ag[0] + k0, AsB[0]);
    async_copy16(Ag[1] + k0, AsB[1]);
    async_copy16(Bg[0] + k0, BsB[0]);
    async_copy16(Bg[1] + k0, BsB[1]);
    __syncthreads();

    bfrag a[4], b[4];
#pragma unroll
    for (int i = 0; i < 4; i++) {
      a[i] = *(const bfrag*)&As[wm + i * 16 + fr][fk];
      b[i] = *(const bfrag*)&Bs[wn + i * 16 + fr][fk];
    }
#pragma unroll
    for (int i = 0; i < 4; i++)
#pragma unroll
      for (int j = 0; j < 4; j++)
        acc[i][j] = __builtin_amdgcn_mfma_f32_16x16x32_bf16(a[i], b[j], acc[i][j], 0, 0, 0);
    __syncthreads();
  }

  const int ccol = lane & 15;
  const int crow = (lane >> 4) * 4;
#pragma unroll
  for (int i = 0; i < 4; i++) {
#pragma unroll
    for (int j = 0; j < 4; j++) {
#pragma unroll
      for (int r = 0; r < 4; r++) {
        const size_t gm = m0 + wm + i * 16 + crow + r;
        const size_t gn = n0 + wn + j * 16 + ccol;
        if (CMODE == 2) {
          ((bf16*)Cv)[gm * N + gn] = __float2bfloat16(acc[i][j][r]);
        } else if (CMODE == 1) {
          float* cp = (float*)Cv + gm * N + gn;
          *cp += acc[i][j][r];
        } else {
          ((float*)Cv)[gm * N + gn] = acc[i][j][r];
        }
      }
    }
  }
}

// ---------------------------------------------------------------------------
// MFMA flash attention (bf16 QK/PV, fp32 softmax state).
// Block = 256 thr = 4 waves; block handles (b, h, 64-q tile); wave wq owns
// q rows [wq*16, wq*16+16). Per 64-key tile:
//   Ks[key][d] (stride 72, d padded 48->64 w/ zeros), Vt[d][key] (transposed
//   on stage via conflict-free paired-key b32 writes), QK^T = 2 ksteps x 4
//   key-tiles of mfma 16x16x32; softmax on C-layout regs; P -> bf16 -> Pt
//   (per-wave slice); PV = 2 ksteps x 3 d-tiles.
// LDS 34.6 KB -> 4 blocks/CU.
// ---------------------------------------------------------------------------
#define AQT 64
#define AKT 64
#define ASTR 72   // LDS row stride: 16B-aligned, uniform bank-group spread

__global__ __launch_bounds__(256, 4) void attn_mfma(
    const bf16* __restrict__ qkv, const float* __restrict__ log_slopes,
    bf16* __restrict__ obuf) {
  __shared__ bf16 Qs[AQT][ASTR];
  __shared__ bf16 Ks[AKT][ASTR];
  __shared__ bf16 Vt[HD][ASTR];
  __shared__ bf16 Pt[AQT][ASTR];

  const int tid = threadIdx.x;
  const int wq = tid >> 6;
  const int lane = tid & 63;
  const int l15 = lane & 15;
  const int lh = lane >> 4;
  const int qb = blockIdx.x * AQT;
  const int h = blockIdx.y;
  const int b = blockIdx.z;

  const float scale = 0.14433756729740643f;  // 1/sqrt(48)
  const float slope = __expf(log_slopes[h]);
  const size_t rstride = 3 * DMODEL;
  const bf16* qbase = qkv + ((size_t)(b * SEQ + qb)) * rstride + h * HD;

  // zero-pad d = 48..63 of Qs, Ks (staging only ever writes d < 48)
  for (int it = tid; it < AQT * 2; it += 256) {
    int r = it >> 1, c = it & 1;
    *(uint4*)&Qs[r][48 + c * 8] = make_uint4(0, 0, 0, 0);
    *(uint4*)&Ks[r][48 + c * 8] = make_uint4(0, 0, 0, 0);
  }
  // stage Q (raw bf16 copy; scale folded into scores)
  for (int it = tid; it < AQT * 6; it += 256) {
    int r = it / 6, c = it % 6;
    *(uint4*)&Qs[r][c * 8] = *(const uint4*)(qbase + (size_t)r * rstride + c * 8);
  }

  float m[4], l[4];
  f32x4 accO[3];
#pragma unroll
  for (int r = 0; r < 4; r++) { m[r] = -1e30f; l[r] = 0.f; }
#pragma unroll
  for (int t = 0; t < 3; t++) accO[t] = (f32x4)(0.f);

  for (int kb = 0; kb < SEQ; kb += AKT) {
    __syncthreads();  // prior iter's LDS reads done (also covers Q/pad stage)
    const bf16* kbase = qkv + ((size_t)(b * SEQ + kb)) * rstride + DMODEL + h * HD;
    // stage K
    for (int it = tid; it < AKT * 6; it += 256) {
      int r = it / 6, c = it % 6;
      *(uint4*)&Ks[r][c * 8] = *(const uint4*)(kbase + (size_t)r * rstride + c * 8);
    }
    // stage V transposed: 32 key-pairs x 6 d-chunks; b32 writes, bank (4i+p)%32
    if (tid < 192) {
      int p = tid & 31, c = tid >> 5;
      const bf16* v0 = kbase + DMODEL + (size_t)(2 * p) * rstride + c * 8;
      uint4 r0 = *(const uint4*)v0;
      uint4 r1 = *(const uint4*)(v0 + rstride);
      const unsigned int* w0 = (const unsigned int*)&r0;
      const unsigned int* w1 = (const unsigned int*)&r1;
#pragma unroll
      for (int i = 0; i < 8; i++) {
        unsigned int lo = (i & 1) ? (w0[i >> 1] >> 16) : (w0[i >> 1] & 0xffffu);
        unsigned int hi = (i & 1) ? (w1[i >> 1] >> 16) : (w1[i >> 1] & 0xffffu);
        *(unsigned int*)&Vt[c * 8 + i][2 * p] = lo | (hi << 16);
      }
    }
    __syncthreads();

    // QK^T
    f32x4 accS[4];
#pragma unroll
    for (int j = 0; j < 4; j++) accS[j] = (f32x4)(0.f);
#pragma unroll
    for (int ks = 0; ks < 2; ks++) {
      bfrag a = *(const bfrag*)&Qs[wq * 16 + l15][ks * 32 + lh * 8];
#pragma unroll
      for (int j = 0; j < 4; j++) {
        bfrag bk = *(const bfrag*)&Ks[j * 16 + l15][ks * 32 + lh * 8];
        accS[j] = __builtin_amdgcn_mfma_f32_16x16x32_bf16(a, bk, accS[j], 0, 0, 0);
      }
    }

    // bias + online softmax; C-layout: row(q) = lh*4 + r, col(key) = l15
    float ps[4][4];
#pragma unroll
    for (int r = 0; r < 4; r++) {
      const int qg = qb + wq * 16 + lh * 4 + r;
      float s[4];
#pragma unroll
      for (int j = 0; j < 4; j++) {
        const int kg = kb + j * 16 + l15;
        s[j] = accS[j][r] * scale - slope * fabsf((float)(qg - kg));
      }
      float mx = fmaxf(fmaxf(s[0], s[1]), fmaxf(s[2], s[3]));
#pragma unroll
      for (int off = 1; off < 16; off <<= 1) mx = fmaxf(mx, __shfl_xor(mx, off, 64));
      const float mnew = fmaxf(m[r], mx);
      const float corr = __expf(m[r] - mnew);
      float rs = 0.f;
#pragma unroll
      for (int j = 0; j < 4; j++) {
        ps[j][r] = __expf(s[j] - mnew);
        rs += ps[j][r];
      }
#pragma unroll
      for (int off = 1; off < 16; off <<= 1) rs += __shfl_xor(rs, off, 64);
      l[r] = l[r] * corr + rs;
      m[r] = mnew;
#pragma unroll
      for (int t = 0; t < 3; t++) accO[t][r] *= corr;
    }

    // P -> per-wave LDS slice Pt[q][key]
#pragma unroll
    for (int j = 0; j < 4; j++)
#pragma unroll
      for (int r = 0; r < 4; r++)
        Pt[wq * 16 + lh * 4 + r][j * 16 + l15] = __float2bfloat16(ps[j][r]);

    // PV (wave-private Pt + shared Vt; in-wave lgkmcnt ordering suffices)
#pragma unroll
    for (int ks = 0; ks < 2; ks++) {
      bfrag pa = *(const bfrag*)&Pt[wq * 16 + l15][ks * 32 + lh * 8];
#pragma unroll
      for (int t = 0; t < 3; t++) {
        bfrag vb = *(const bfrag*)&Vt[t * 16 + l15][ks * 32 + lh * 8];
        accO[t] = __builtin_amdgcn_mfma_f32_16x16x32_bf16(pa, vb, accO[t], 0, 0, 0);
      }
    }
  }

  // epilogue: O / l -> obuf (C-layout: row q = lh*4+r, col d = t*16 + l15)
#pragma unroll
  for (int r = 0; r < 4; r++) {
    const float inv = 1.0f / l[r];
    bf16* op = obuf + ((size_t)(b * SEQ + qb + wq * 16 + lh * 4 + r)) * DMODEL + h * HD;
#pragma unroll
    for (int t = 0; t < 3; t++)
      op[t * 16 + l15] = __float2bfloat16(accO[t][r] * inv);
  }
}

// ---------------------------------------------------------------------------
// gu = silu(g) * u, bf16 in/out, packed pairs
// ---------------------------------------------------------------------------
__global__ __launch_bounds__(256) void silu_mul_kernel(
    bf16* __restrict__ g, const bf16* __restrict__ u, size_t n2) {
  size_t i = (size_t)blockIdx.x * blockDim.x + threadIdx.x;
  size_t stride = (size_t)gridDim.x * blockDim.x;
  unsigned int* gp = (unsigned int*)g;
  const unsigned int* up = (const unsigned int*)u;
  for (; i < n2; i += stride) {
    unsigned int gu_ = gp[i], uu = up[i];
    float g0 = bflo(gu_), g1 = bfhi(gu_);
    float u0 = bflo(uu), u1 = bfhi(uu);
    float r0 = g0 / (1.0f + __expf(-g0)) * u0;
    float r1 = g1 / (1.0f + __expf(-g1)) * u1;
    gp[i] = (unsigned int)f2bf_raw(r0) | ((unsigned int)f2bf_raw(r1) << 16);
  }
}

// ---------------------------------------------------------------------------
// launcher
// ---------------------------------------------------------------------------
extern "C" void kernel_launch(void* const* d_in, const int* in_sizes, int n_in,
                              void* d_out, int out_size, void* d_ws, size_t ws_size,
                              hipStream_t stream) {
  const float* cls_tokens = (const float*)d_in[0];
  const float* cls_token  = (const float*)d_in[1];
  const float* log_slopes = (const float*)d_in[2];
  const float* Wqkv = (const float*)d_in[3];
  const float* Wo   = (const float*)d_in[4];
  const float* Wg   = (const float*)d_in[5];
  const float* Wu   = (const float*)d_in[6];
  const float* Wd   = (const float*)d_in[7];
  const float* ln1_w = (const float*)d_in[8];
  const float* ln1_b = (const float*)d_in[9];
  const float* ln2_w = (const float*)d_in[10];
  const float* ln2_b = (const float*)d_in[11];
  const float* fin_w = (const float*)d_in[12];
  const float* fin_b = (const float*)d_in[13];
  float* out = (float*)d_out;

  const size_t ROWS = (size_t)BATCH * SEQ;  // 4096
  char* wsb = (char*)d_ws;
  float* x    = (float*)(wsb);                       // 12,582,912 B
  bf16* qkvb  = (bf16*)(wsb + 12582912);             // 18,874,368 B
  bf16* hb    = (bf16*)(wsb + 31457280);             //  6,291,456 B
  bf16* ob    = (bf16*)(wsb + 37748736);             //  6,291,456 B
  bf16* gb    = (bf16*)(wsb + 44040192);             // 25,165,824 B
  bf16* ub    = (bf16*)(wsb + 69206016);             // 25,165,824 B
  bf16* wbf   = (bf16*)(wsb + 94371840);             // 18,874,368 B

  bf16* wqkv_b = wbf;
  bf16* wo_b   = wbf + 1769472;
  bf16* wg_b   = wbf + 2359296;
  bf16* wu_b   = wbf + 4718592;
  bf16* wd_b   = wbf + 7077888;

  {
    const size_t total = ROWS * DMODEL;
    concat_kernel<<<(int)((total + 255) / 256), 256, 0, stream>>>(cls_tokens, cls_token, x);
  }

  for (int l = 0; l < LNUM; l++) {
    convert_w_kernel<<<9216, 256, 0, stream>>>(
        Wqkv + (size_t)l * 3 * DMODEL * DMODEL, Wo + (size_t)l * DMODEL * DMODEL,
        Wg + (size_t)l * FFDIM * DMODEL, Wu + (size_t)l * FFDIM * DMODEL,
        Wd + (size_t)l * DMODEL * FFDIM, wbf);

    ln_kernel<bf16><<<(int)ROWS, 256, 0, stream>>>(
        x, hb, ln1_w + l * DMODEL, ln1_b + l * DMODEL, DMODEL, DMODEL);
    gemm_bf16<2><<<dim3(3 * DMODEL / BN, ROWS / BM), 256, 0, stream>>>(
        hb, wqkv_b, qkvb, (int)ROWS, 3 * DMODEL, DMODEL);
    attn_mfma<<<dim3(SEQ / AQT, HNUM, BATCH), 256, 0, stream>>>(qkvb, log_slopes, ob);
    gemm_bf16<1><<<dim3(DMODEL / BN, ROWS / BM), 256, 0, stream>>>(
        ob, wo_b, x, (int)ROWS, DMODEL, DMODEL);
    ln_kernel<bf16><<<(int)ROWS, 256, 0, stream>>>(
        x, hb, ln2_w + l * DMODEL, ln2_b + l * DMODEL, DMODEL, DMODEL);
    gemm_bf16<2><<<dim3(FFDIM / BN, ROWS / BM), 256, 0, stream>>>(
        hb, wg_b, gb, (int)ROWS, FFDIM, DMODEL);
    gemm_bf16<2><<<dim3(FFDIM / BN, ROWS / BM), 256, 0, stream>>>(
        hb, wu_b, ub, (int)ROWS, FFDIM, DMODEL);
    silu_mul_kernel<<<4096, 256, 0, stream>>>(gb, ub, ROWS * FFDIM / 2);
    gemm_bf16<1><<<dim3(DMODEL / BN, ROWS / BM), 256, 0, stream>>>(
        gb, wd_b, x, (int)ROWS, DMODEL, FFDIM);
  }

  ln_kernel<float><<<BATCH, 256, 0, stream>>>(x, out, fin_w, fin_b,
                                              (size_t)SEQ * DMODEL, DMODEL);
}

// Round 5
// 1885.959 us; speedup vs baseline: 14.7896x; 1.0876x over previous
//
#include <hip/hip_runtime.h>
#include <hip/hip_bf16.h>

// Problem constants
#define LNUM 6
#define HNUM 16
#define DMODEL 768
#define FFDIM 3072
#define BATCH 4
#define NTOK 1023
#define SEQ 1024          // NTOK + 1
#define HD 48             // DMODEL / HNUM
#define EPS 1e-5f

typedef __hip_bfloat16 bf16;

__device__ __forceinline__ unsigned short f2bf_raw(float f) {
  bf16 h = __float2bfloat16(f);
  union { bf16 h; unsigned short s; } u; u.h = h; return u.s;
}
__device__ __forceinline__ float bflo(unsigned int u) { return __uint_as_float(u << 16); }
__device__ __forceinline__ float bfhi(unsigned int u) { return __uint_as_float(u & 0xffff0000u); }

// ---------------------------------------------------------------------------
// concat: x[b,s,:] = s==0 ? cls_token : cls_tokens[b,s-1,:]  (fp32 residual)
// ---------------------------------------------------------------------------
__global__ __launch_bounds__(256) void concat_kernel(
    const float* __restrict__ cls_tokens, const float* __restrict__ cls_token,
    float* __restrict__ x) {
  size_t i = (size_t)blockIdx.x * blockDim.x + threadIdx.x;
  const size_t total = (size_t)BATCH * SEQ * DMODEL;
  if (i >= total) return;
  int d = (int)(i % DMODEL);
  size_t bs = i / DMODEL;
  int s = (int)(bs % SEQ);
  int b = (int)(bs / SEQ);
  float v;
  if (s == 0) v = cls_token[d];
  else v = cls_tokens[((size_t)b * NTOK + (s - 1)) * DMODEL + d];
  x[i] = v;
}

// ---------------------------------------------------------------------------
// per-layer weight pack fp32 -> bf16 (Wqkv | Wo | Wg | Wu | Wd concatenated)
// ---------------------------------------------------------------------------
#define W_QKV4  442368
#define W_O4    147456
#define W_FF4   589824
__global__ __launch_bounds__(256) void convert_w_kernel(
    const float* __restrict__ wqkv, const float* __restrict__ wo,
    const float* __restrict__ wg, const float* __restrict__ wu,
    const float* __restrict__ wd, bf16* __restrict__ dst) {
  size_t i4 = (size_t)blockIdx.x * 256 + threadIdx.x;
  size_t off4 = i4;
  const float* src;
  if (off4 < W_QKV4) src = wqkv;
  else { off4 -= W_QKV4;
    if (off4 < W_O4) src = wo;
    else { off4 -= W_O4;
      if (off4 < W_FF4) src = wg;
      else { off4 -= W_FF4;
        if (off4 < W_FF4) src = wu;
        else { off4 -= W_FF4; src = wd; } } } }
  float4 v = ((const float4*)src)[off4];
  ushort4 o;
  o.x = f2bf_raw(v.x); o.y = f2bf_raw(v.y);
  o.z = f2bf_raw(v.z); o.w = f2bf_raw(v.w);
  ((ushort4*)dst)[i4] = o;
}

// ---------------------------------------------------------------------------
// layernorm: one 256-thread block per row of 768. OUT = float or bf16.
// ---------------------------------------------------------------------------
__device__ __forceinline__ void st_ln(float* p, float v) { *p = v; }
__device__ __forceinline__ void st_ln(bf16* p, float v) { *p = __float2bfloat16(v); }

template <typename OUT>
__global__ __launch_bounds__(256) void ln_kernel(
    const float* __restrict__ in, OUT* __restrict__ out,
    const float* __restrict__ w, const float* __restrict__ bias,
    size_t in_stride, size_t out_stride) {
  const int row = blockIdx.x;
  const int tid = threadIdx.x;
  const float* x = in + (size_t)row * in_stride;
  OUT* y = out + (size_t)row * out_stride;

  float v0 = x[tid], v1 = x[tid + 256], v2 = x[tid + 512];
  float s = v0 + v1 + v2;
  float sq = v0 * v0 + v1 * v1 + v2 * v2;

  __shared__ float s_sum[256];
  __shared__ float s_sq[256];
  s_sum[tid] = s;
  s_sq[tid] = sq;
  __syncthreads();
  for (int off = 128; off > 0; off >>= 1) {
    if (tid < off) {
      s_sum[tid] += s_sum[tid + off];
      s_sq[tid] += s_sq[tid + off];
    }
    __syncthreads();
  }
  const float inv_d = 1.0f / (float)DMODEL;
  float mean = s_sum[0] * inv_d;
  float var = s_sq[0] * inv_d - mean * mean;
  float rstd = rsqrtf(var + EPS);

  st_ln(y + tid,       (v0 - mean) * rstd * w[tid]       + bias[tid]);
  st_ln(y + tid + 256, (v1 - mean) * rstd * w[tid + 256] + bias[tid + 256]);
  st_ln(y + tid + 512, (v2 - mean) * rstd * w[tid + 512] + bias[tid + 512]);
}

// ---------------------------------------------------------------------------
// bf16 MFMA NT GEMM, double-buffered LDS pipeline.
// C[m,n] = sum_k A[m,k]*B[n,k]; 128x128 tile, BK=32, 4 waves (2x2).
// Stage for iter k+1 is issued right AFTER the barrier so its latency hides
// behind iter k's compute; next barrier's vmcnt(0) drains it.
// CMODE: 0 = store fp32, 1 = accumulate fp32, 2 = store bf16.
// ---------------------------------------------------------------------------
#define BM 128
#define BN 128
#define BK 32

typedef __attribute__((ext_vector_type(8))) short bfrag;
typedef __attribute__((ext_vector_type(4))) float f32x4;

__device__ __forceinline__ void async_copy16(const void* g, void* l) {
  __builtin_amdgcn_global_load_lds(
      (const __attribute__((address_space(1))) void*)g,
      (__attribute__((address_space(3))) void*)l, 16, 0, 0);
}

template <int CMODE>
__global__ __launch_bounds__(256) void gemm_bf16(
    const bf16* __restrict__ A, const bf16* __restrict__ B,
    void* __restrict__ Cv, int M, int N, int K) {
  __shared__ bf16 As[2][BM][BK];  // 16 KB
  __shared__ bf16 Bs[2][BN][BK];  // 16 KB

  const int tid = threadIdx.x;
  const int wave = tid >> 6;
  const int lane = tid & 63;
  const int m0 = blockIdx.y * BM;
  const int n0 = blockIdx.x * BN;
  const int wm = (wave & 1) * 64;
  const int wn = (wave >> 1) * 64;

  f32x4 acc[4][4];
#pragma unroll
  for (int i = 0; i < 4; i++)
#pragma unroll
    for (int j = 0; j < 4; j++) acc[i][j] = (f32x4)(0.f);

  const int lrow = lane >> 2;
  const int lcol = (lane & 3) * 8;
  const bf16* Ag[2]; const bf16* Bg[2];
  void *AsB[2][2], *BsB[2][2];   // [buf][chunk]
#pragma unroll
  for (int j = 0; j < 2; j++) {
    int c = j * 4 + wave;
    Ag[j] = A + (size_t)(m0 + c * 16 + lrow) * K + lcol;
    Bg[j] = B + (size_t)(n0 + c * 16 + lrow) * K + lcol;
#pragma unroll
    for (int bf = 0; bf < 2; bf++) {
      AsB[bf][j] = (void*)&As[bf][c * 16][0];
      BsB[bf][j] = (void*)&Bs[bf][c * 16][0];
    }
  }

  // prologue: stage buf 0
#pragma unroll
  for (int j = 0; j < 2; j++) {
    async_copy16(Ag[j], AsB[0][j]);
    async_copy16(Bg[j], BsB[0][j]);
  }

  const int fr = lane & 15;
  const int fk = (lane >> 4) * 8;
  const int nk = K / BK;

  for (int ki = 0; ki < nk; ki++) {
    const int cur = ki & 1;
    __syncthreads();  // buf[cur] staged; prior reads of buf[cur^1] done
    if (ki + 1 < nk) {
      const int k0 = (ki + 1) * BK;
#pragma unroll
      for (int j = 0; j < 2; j++) {
        async_copy16(Ag[j] + k0, AsB[cur ^ 1][j]);
        async_copy16(Bg[j] + k0, BsB[cur ^ 1][j]);
      }
    }
    bfrag a[4], b[4];
#pragma unroll
    for (int i = 0; i < 4; i++) {
      a[i] = *(const bfrag*)&As[cur][wm + i * 16 + fr][fk];
      b[i] = *(const bfrag*)&Bs[cur][wn + i * 16 + fr][fk];
    }
#pragma unroll
    for (int i = 0; i < 4; i++)
#pragma unroll
      for (int j = 0; j < 4; j++)
        acc[i][j] = __builtin_amdgcn_mfma_f32_16x16x32_bf16(a[i], b[j], acc[i][j], 0, 0, 0);
  }

  const int ccol = lane & 15;
  const int crow = (lane >> 4) * 4;
#pragma unroll
  for (int i = 0; i < 4; i++) {
#pragma unroll
    for (int j = 0; j < 4; j++) {
#pragma unroll
      for (int r = 0; r < 4; r++) {
        const size_t gm = m0 + wm + i * 16 + crow + r;
        const size_t gn = n0 + wn + j * 16 + ccol;
        if (CMODE == 2) {
          ((bf16*)Cv)[gm * N + gn] = __float2bfloat16(acc[i][j][r]);
        } else if (CMODE == 1) {
          float* cp = (float*)Cv + gm * N + gn;
          *cp += acc[i][j][r];
        } else {
          ((float*)Cv)[gm * N + gn] = acc[i][j][r];
        }
      }
    }
  }
}

// ---------------------------------------------------------------------------
// Fused gate+up GEMM with silu epilogue:
//   gu[m,n] = silu(A[m,:]·Wg[n,:]) * (A[m,:]·Wu[n,:])
// Same dbuf structure; 3 staged matrices (A, Wg, Wu), 32 MFMA/wave/iter.
// LDS 48 KB; ~208 regs -> 2 waves/SIMD, 2 blocks/CU.
// ---------------------------------------------------------------------------
__global__ __launch_bounds__(256) void gemm_gateup(
    const bf16* __restrict__ A, const bf16* __restrict__ Wg,
    const bf16* __restrict__ Wu, bf16* __restrict__ gu, int M, int N, int K) {
  __shared__ bf16 As[2][BM][BK];
  __shared__ bf16 Gs[2][BN][BK];
  __shared__ bf16 Us[2][BN][BK];

  const int tid = threadIdx.x;
  const int wave = tid >> 6;
  const int lane = tid & 63;
  const int m0 = blockIdx.y * BM;
  const int n0 = blockIdx.x * BN;
  const int wm = (wave & 1) * 64;
  const int wn = (wave >> 1) * 64;

  f32x4 accG[4][4], accU[4][4];
#pragma unroll
  for (int i = 0; i < 4; i++)
#pragma unroll
    for (int j = 0; j < 4; j++) { accG[i][j] = (f32x4)(0.f); accU[i][j] = (f32x4)(0.f); }

  const int lrow = lane >> 2;
  const int lcol = (lane & 3) * 8;
  const bf16 *Ag[2], *Gg[2], *Ug[2];
  void *AsB[2][2], *GsB[2][2], *UsB[2][2];
#pragma unroll
  for (int j = 0; j < 2; j++) {
    int c = j * 4 + wave;
    Ag[j] = A + (size_t)(m0 + c * 16 + lrow) * K + lcol;
    Gg[j] = Wg + (size_t)(n0 + c * 16 + lrow) * K + lcol;
    Ug[j] = Wu + (size_t)(n0 + c * 16 + lrow) * K + lcol;
#pragma unroll
    for (int bf = 0; bf < 2; bf++) {
      AsB[bf][j] = (void*)&As[bf][c * 16][0];
      GsB[bf][j] = (void*)&Gs[bf][c * 16][0];
      UsB[bf][j] = (void*)&Us[bf][c * 16][0];
    }
  }

#pragma unroll
  for (int j = 0; j < 2; j++) {
    async_copy16(Ag[j], AsB[0][j]);
    async_copy16(Gg[j], GsB[0][j]);
    async_copy16(Ug[j], UsB[0][j]);
  }

  const int fr = lane & 15;
  const int fk = (lane >> 4) * 8;
  const int nk = K / BK;

  for (int ki = 0; ki < nk; ki++) {
    const int cur = ki & 1;
    __syncthreads();
    if (ki + 1 < nk) {
      const int k0 = (ki + 1) * BK;
#pragma unroll
      for (int j = 0; j < 2; j++) {
        async_copy16(Ag[j] + k0, AsB[cur ^ 1][j]);
        async_copy16(Gg[j] + k0, GsB[cur ^ 1][j]);
        async_copy16(Ug[j] + k0, UsB[cur ^ 1][j]);
      }
    }
    bfrag a[4], g[4], u[4];
#pragma unroll
    for (int i = 0; i < 4; i++) {
      a[i] = *(const bfrag*)&As[cur][wm + i * 16 + fr][fk];
      g[i] = *(const bfrag*)&Gs[cur][wn + i * 16 + fr][fk];
      u[i] = *(const bfrag*)&Us[cur][wn + i * 16 + fr][fk];
    }
#pragma unroll
    for (int i = 0; i < 4; i++)
#pragma unroll
      for (int j = 0; j < 4; j++) {
        accG[i][j] = __builtin_amdgcn_mfma_f32_16x16x32_bf16(a[i], g[j], accG[i][j], 0, 0, 0);
        accU[i][j] = __builtin_amdgcn_mfma_f32_16x16x32_bf16(a[i], u[j], accU[i][j], 0, 0, 0);
      }
  }

  const int ccol = lane & 15;
  const int crow = (lane >> 4) * 4;
#pragma unroll
  for (int i = 0; i < 4; i++) {
#pragma unroll
    for (int j = 0; j < 4; j++) {
#pragma unroll
      for (int r = 0; r < 4; r++) {
        const size_t gm = m0 + wm + i * 16 + crow + r;
        const size_t gn = n0 + wn + j * 16 + ccol;
        const float gv = accG[i][j][r];
        const float uv = accU[i][j][r];
        const float res = gv / (1.0f + __expf(-gv)) * uv;
        gu[gm * N + gn] = __float2bfloat16(res);
      }
    }
  }
}

// ---------------------------------------------------------------------------
// MFMA flash attention (bf16 QK/PV, fp32 softmax state). See round-4 notes.
// ---------------------------------------------------------------------------
#define AQT 64
#define AKT 64
#define ASTR 72

__global__ __launch_bounds__(256, 4) void attn_mfma(
    const bf16* __restrict__ qkv, const float* __restrict__ log_slopes,
    bf16* __restrict__ obuf) {
  __shared__ bf16 Qs[AQT][ASTR];
  __shared__ bf16 Ks[AKT][ASTR];
  __shared__ bf16 Vt[HD][ASTR];
  __shared__ bf16 Pt[AQT][ASTR];

  const int tid = threadIdx.x;
  const int wq = tid >> 6;
  const int lane = tid & 63;
  const int l15 = lane & 15;
  const int lh = lane >> 4;
  const int qb = blockIdx.x * AQT;
  const int h = blockIdx.y;
  const int b = blockIdx.z;

  const float scale = 0.14433756729740643f;  // 1/sqrt(48)
  const float slope = __expf(log_slopes[h]);
  const size_t rstride = 3 * DMODEL;
  const bf16* qbase = qkv + ((size_t)(b * SEQ + qb)) * rstride + h * HD;

  for (int it = tid; it < AQT * 2; it += 256) {
    int r = it >> 1, c = it & 1;
    *(uint4*)&Qs[r][48 + c * 8] = make_uint4(0, 0, 0, 0);
    *(uint4*)&Ks[r][48 + c * 8] = make_uint4(0, 0, 0, 0);
  }
  for (int it = tid; it < AQT * 6; it += 256) {
    int r = it / 6, c = it % 6;
    *(uint4*)&Qs[r][c * 8] = *(const uint4*)(qbase + (size_t)r * rstride + c * 8);
  }

  float m[4], l[4];
  f32x4 accO[3];
#pragma unroll
  for (int r = 0; r < 4; r++) { m[r] = -1e30f; l[r] = 0.f; }
#pragma unroll
  for (int t = 0; t < 3; t++) accO[t] = (f32x4)(0.f);

  for (int kb = 0; kb < SEQ; kb += AKT) {
    __syncthreads();
    const bf16* kbase = qkv + ((size_t)(b * SEQ + kb)) * rstride + DMODEL + h * HD;
    for (int it = tid; it < AKT * 6; it += 256) {
      int r = it / 6, c = it % 6;
      *(uint4*)&Ks[r][c * 8] = *(const uint4*)(kbase + (size_t)r * rstride + c * 8);
    }
    if (tid < 192) {
      int p = tid & 31, c = tid >> 5;
      const bf16* v0 = kbase + DMODEL + (size_t)(2 * p) * rstride + c * 8;
      uint4 r0 = *(const uint4*)v0;
      uint4 r1 = *(const uint4*)(v0 + rstride);
      const unsigned int* w0 = (const unsigned int*)&r0;
      const unsigned int* w1 = (const unsigned int*)&r1;
#pragma unroll
      for (int i = 0; i < 8; i++) {
        unsigned int lo = (i & 1) ? (w0[i >> 1] >> 16) : (w0[i >> 1] & 0xffffu);
        unsigned int hi = (i & 1) ? (w1[i >> 1] >> 16) : (w1[i >> 1] & 0xffffu);
        *(unsigned int*)&Vt[c * 8 + i][2 * p] = lo | (hi << 16);
      }
    }
    __syncthreads();

    f32x4 accS[4];
#pragma unroll
    for (int j = 0; j < 4; j++) accS[j] = (f32x4)(0.f);
#pragma unroll
    for (int ks = 0; ks < 2; ks++) {
      bfrag a = *(const bfrag*)&Qs[wq * 16 + l15][ks * 32 + lh * 8];
#pragma unroll
      for (int j = 0; j < 4; j++) {
        bfrag bk = *(const bfrag*)&Ks[j * 16 + l15][ks * 32 + lh * 8];
        accS[j] = __builtin_amdgcn_mfma_f32_16x16x32_bf16(a, bk, accS[j], 0, 0, 0);
      }
    }

    float ps[4][4];
#pragma unroll
    for (int r = 0; r < 4; r++) {
      const int qg = qb + wq * 16 + lh * 4 + r;
      float s[4];
#pragma unroll
      for (int j = 0; j < 4; j++) {
        const int kg = kb + j * 16 + l15;
        s[j] = accS[j][r] * scale - slope * fabsf((float)(qg - kg));
      }
      float mx = fmaxf(fmaxf(s[0], s[1]), fmaxf(s[2], s[3]));
#pragma unroll
      for (int off = 1; off < 16; off <<= 1) mx = fmaxf(mx, __shfl_xor(mx, off, 64));
      const float mnew = fmaxf(m[r], mx);
      const float corr = __expf(m[r] - mnew);
      float rs = 0.f;
#pragma unroll
      for (int j = 0; j < 4; j++) {
        ps[j][r] = __expf(s[j] - mnew);
        rs += ps[j][r];
      }
#pragma unroll
      for (int off = 1; off < 16; off <<= 1) rs += __shfl_xor(rs, off, 64);
      l[r] = l[r] * corr + rs;
      m[r] = mnew;
#pragma unroll
      for (int t = 0; t < 3; t++) accO[t][r] *= corr;
    }

#pragma unroll
    for (int j = 0; j < 4; j++)
#pragma unroll
      for (int r = 0; r < 4; r++)
        Pt[wq * 16 + lh * 4 + r][j * 16 + l15] = __float2bfloat16(ps[j][r]);

#pragma unroll
    for (int ks = 0; ks < 2; ks++) {
      bfrag pa = *(const bfrag*)&Pt[wq * 16 + l15][ks * 32 + lh * 8];
#pragma unroll
      for (int t = 0; t < 3; t++) {
        bfrag vb = *(const bfrag*)&Vt[t * 16 + l15][ks * 32 + lh * 8];
        accO[t] = __builtin_amdgcn_mfma_f32_16x16x32_bf16(pa, vb, accO[t], 0, 0, 0);
      }
    }
  }

#pragma unroll
  for (int r = 0; r < 4; r++) {
    const float inv = 1.0f / l[r];
    bf16* op = obuf + ((size_t)(b * SEQ + qb + wq * 16 + lh * 4 + r)) * DMODEL + h * HD;
#pragma unroll
    for (int t = 0; t < 3; t++)
      op[t * 16 + l15] = __float2bfloat16(accO[t][r] * inv);
  }
}

// ---------------------------------------------------------------------------
// launcher
// ---------------------------------------------------------------------------
extern "C" void kernel_launch(void* const* d_in, const int* in_sizes, int n_in,
                              void* d_out, int out_size, void* d_ws, size_t ws_size,
                              hipStream_t stream) {
  const float* cls_tokens = (const float*)d_in[0];
  const float* cls_token  = (const float*)d_in[1];
  const float* log_slopes = (const float*)d_in[2];
  const float* Wqkv = (const float*)d_in[3];
  const float* Wo   = (const float*)d_in[4];
  const float* Wg   = (const float*)d_in[5];
  const float* Wu   = (const float*)d_in[6];
  const float* Wd   = (const float*)d_in[7];
  const float* ln1_w = (const float*)d_in[8];
  const float* ln1_b = (const float*)d_in[9];
  const float* ln2_w = (const float*)d_in[10];
  const float* ln2_b = (const float*)d_in[11];
  const float* fin_w = (const float*)d_in[12];
  const float* fin_b = (const float*)d_in[13];
  float* out = (float*)d_out;

  const size_t ROWS = (size_t)BATCH * SEQ;  // 4096
  char* wsb = (char*)d_ws;
  float* x    = (float*)(wsb);                       // 12,582,912 B
  bf16* qkvb  = (bf16*)(wsb + 12582912);             // 18,874,368 B
  bf16* hb    = (bf16*)(wsb + 31457280);             //  6,291,456 B
  bf16* ob    = (bf16*)(wsb + 37748736);             //  6,291,456 B
  bf16* gub   = (bf16*)(wsb + 44040192);             // 25,165,824 B
  bf16* wbf   = (bf16*)(wsb + 94371840);             // 18,874,368 B

  bf16* wqkv_b = wbf;
  bf16* wo_b   = wbf + 1769472;
  bf16* wg_b   = wbf + 2359296;
  bf16* wu_b   = wbf + 4718592;
  bf16* wd_b   = wbf + 7077888;

  {
    const size_t total = ROWS * DMODEL;
    concat_kernel<<<(int)((total + 255) / 256), 256, 0, stream>>>(cls_tokens, cls_token, x);
  }

  for (int l = 0; l < LNUM; l++) {
    convert_w_kernel<<<9216, 256, 0, stream>>>(
        Wqkv + (size_t)l * 3 * DMODEL * DMODEL, Wo + (size_t)l * DMODEL * DMODEL,
        Wg + (size_t)l * FFDIM * DMODEL, Wu + (size_t)l * FFDIM * DMODEL,
        Wd + (size_t)l * DMODEL * FFDIM, wbf);

    ln_kernel<bf16><<<(int)ROWS, 256, 0, stream>>>(
        x, hb, ln1_w + l * DMODEL, ln1_b + l * DMODEL, DMODEL, DMODEL);
    gemm_bf16<2><<<dim3(3 * DMODEL / BN, ROWS / BM), 256, 0, stream>>>(
        hb, wqkv_b, qkvb, (int)ROWS, 3 * DMODEL, DMODEL);
    attn_mfma<<<dim3(SEQ / AQT, HNUM, BATCH), 256, 0, stream>>>(qkvb, log_slopes, ob);
    gemm_bf16<1><<<dim3(DMODEL / BN, ROWS / BM), 256, 0, stream>>>(
        ob, wo_b, x, (int)ROWS, DMODEL, DMODEL);
    ln_kernel<bf16><<<(int)ROWS, 256, 0, stream>>>(
        x, hb, ln2_w + l * DMODEL, ln2_b + l * DMODEL, DMODEL, DMODEL);
    gemm_gateup<<<dim3(FFDIM / BN, ROWS / BM), 256, 0, stream>>>(
        hb, wg_b, wu_b, gub, (int)ROWS, FFDIM, DMODEL);
    gemm_bf16<1><<<dim3(DMODEL / BN, ROWS / BM), 256, 0, stream>>>(
        gub, wd_b, x, (int)ROWS, DMODEL, FFDIM);
  }

  ln_kernel<float><<<BATCH, 256, 0, stream>>>(x, out, fin_w, fin_b,
                                              (size_t)SEQ * DMODEL, DMODEL);
}

// Round 6
// 1848.254 us; speedup vs baseline: 15.0913x; 1.0204x over previous
//
#include <hip/hip_runtime.h>
#include <hip/hip_bf16.h>

// Problem constants
#define LNUM 6
#define HNUM 16
#define DMODEL 768
#define FFDIM 3072
#define BATCH 4
#define NTOK 1023
#define SEQ 1024          // NTOK + 1
#define HD 48             // DMODEL / HNUM
#define EPS 1e-5f

typedef __hip_bfloat16 bf16;

__device__ __forceinline__ unsigned short f2bf_raw(float f) {
  bf16 h = __float2bfloat16(f);
  union { bf16 h; unsigned short s; } u; u.h = h; return u.s;
}
__device__ __forceinline__ float bflo(unsigned int u) { return __uint_as_float(u << 16); }
__device__ __forceinline__ float bfhi(unsigned int u) { return __uint_as_float(u & 0xffff0000u); }

// ---------------------------------------------------------------------------
// concat: x[b,s,:] = s==0 ? cls_token : cls_tokens[b,s-1,:]  (fp32 residual)
// ---------------------------------------------------------------------------
__global__ __launch_bounds__(256) void concat_kernel(
    const float* __restrict__ cls_tokens, const float* __restrict__ cls_token,
    float* __restrict__ x) {
  size_t i = (size_t)blockIdx.x * blockDim.x + threadIdx.x;
  const size_t total = (size_t)BATCH * SEQ * DMODEL;
  if (i >= total) return;
  int d = (int)(i % DMODEL);
  size_t bs = i / DMODEL;
  int s = (int)(bs % SEQ);
  int b = (int)(bs / SEQ);
  float v;
  if (s == 0) v = cls_token[d];
  else v = cls_tokens[((size_t)b * NTOK + (s - 1)) * DMODEL + d];
  x[i] = v;
}

// ---------------------------------------------------------------------------
// per-layer weight pack fp32 -> bf16 (Wqkv | Wo | Wg | Wu | Wd concatenated)
// ---------------------------------------------------------------------------
#define W_QKV4  442368
#define W_O4    147456
#define W_FF4   589824
__global__ __launch_bounds__(256) void convert_w_kernel(
    const float* __restrict__ wqkv, const float* __restrict__ wo,
    const float* __restrict__ wg, const float* __restrict__ wu,
    const float* __restrict__ wd, bf16* __restrict__ dst) {
  size_t i4 = (size_t)blockIdx.x * 256 + threadIdx.x;
  size_t off4 = i4;
  const float* src;
  if (off4 < W_QKV4) src = wqkv;
  else { off4 -= W_QKV4;
    if (off4 < W_O4) src = wo;
    else { off4 -= W_O4;
      if (off4 < W_FF4) src = wg;
      else { off4 -= W_FF4;
        if (off4 < W_FF4) src = wu;
        else { off4 -= W_FF4; src = wd; } } } }
  float4 v = ((const float4*)src)[off4];
  ushort4 o;
  o.x = f2bf_raw(v.x); o.y = f2bf_raw(v.y);
  o.z = f2bf_raw(v.z); o.w = f2bf_raw(v.w);
  ((ushort4*)dst)[i4] = o;
}

// ---------------------------------------------------------------------------
// layernorm: one 256-thread block per row of 768. OUT = float or bf16.
// ---------------------------------------------------------------------------
__device__ __forceinline__ void st_ln(float* p, float v) { *p = v; }
__device__ __forceinline__ void st_ln(bf16* p, float v) { *p = __float2bfloat16(v); }

template <typename OUT>
__global__ __launch_bounds__(256) void ln_kernel(
    const float* __restrict__ in, OUT* __restrict__ out,
    const float* __restrict__ w, const float* __restrict__ bias,
    size_t in_stride, size_t out_stride) {
  const int row = blockIdx.x;
  const int tid = threadIdx.x;
  const float* x = in + (size_t)row * in_stride;
  OUT* y = out + (size_t)row * out_stride;

  float v0 = x[tid], v1 = x[tid + 256], v2 = x[tid + 512];
  float s = v0 + v1 + v2;
  float sq = v0 * v0 + v1 * v1 + v2 * v2;

  __shared__ float s_sum[256];
  __shared__ float s_sq[256];
  s_sum[tid] = s;
  s_sq[tid] = sq;
  __syncthreads();
  for (int off = 128; off > 0; off >>= 1) {
    if (tid < off) {
      s_sum[tid] += s_sum[tid + off];
      s_sq[tid] += s_sq[tid + off];
    }
    __syncthreads();
  }
  const float inv_d = 1.0f / (float)DMODEL;
  float mean = s_sum[0] * inv_d;
  float var = s_sq[0] * inv_d - mean * mean;
  float rstd = rsqrtf(var + EPS);

  st_ln(y + tid,       (v0 - mean) * rstd * w[tid]       + bias[tid]);
  st_ln(y + tid + 256, (v1 - mean) * rstd * w[tid + 256] + bias[tid + 256]);
  st_ln(y + tid + 512, (v2 - mean) * rstd * w[tid + 512] + bias[tid + 512]);
}

// ---------------------------------------------------------------------------
// bf16 MFMA NT GEMM, double-buffered LDS pipeline. 128x128 tile, BK=32.
// CMODE: 0 = store fp32, 1 = accumulate fp32, 2 = store bf16.
// ---------------------------------------------------------------------------
#define BM 128
#define BN 128
#define BK 32

typedef __attribute__((ext_vector_type(8))) short bfrag;
typedef __attribute__((ext_vector_type(4))) float f32x4;

__device__ __forceinline__ void async_copy16(const void* g, void* l) {
  __builtin_amdgcn_global_load_lds(
      (const __attribute__((address_space(1))) void*)g,
      (__attribute__((address_space(3))) void*)l, 16, 0, 0);
}

template <int CMODE>
__global__ __launch_bounds__(256) void gemm_bf16(
    const bf16* __restrict__ A, const bf16* __restrict__ B,
    void* __restrict__ Cv, int M, int N, int K) {
  __shared__ bf16 As[2][BM][BK];  // 16 KB
  __shared__ bf16 Bs[2][BN][BK];  // 16 KB

  const int tid = threadIdx.x;
  const int wave = tid >> 6;
  const int lane = tid & 63;
  const int m0 = blockIdx.y * BM;
  const int n0 = blockIdx.x * BN;
  const int wm = (wave & 1) * 64;
  const int wn = (wave >> 1) * 64;

  f32x4 acc[4][4];
#pragma unroll
  for (int i = 0; i < 4; i++)
#pragma unroll
    for (int j = 0; j < 4; j++) acc[i][j] = (f32x4)(0.f);

  const int lrow = lane >> 2;
  const int lcol = (lane & 3) * 8;
  const bf16* Ag[2]; const bf16* Bg[2];
  void *AsB[2][2], *BsB[2][2];   // [buf][chunk]
#pragma unroll
  for (int j = 0; j < 2; j++) {
    int c = j * 4 + wave;
    Ag[j] = A + (size_t)(m0 + c * 16 + lrow) * K + lcol;
    Bg[j] = B + (size_t)(n0 + c * 16 + lrow) * K + lcol;
#pragma unroll
    for (int bf = 0; bf < 2; bf++) {
      AsB[bf][j] = (void*)&As[bf][c * 16][0];
      BsB[bf][j] = (void*)&Bs[bf][c * 16][0];
    }
  }

#pragma unroll
  for (int j = 0; j < 2; j++) {
    async_copy16(Ag[j], AsB[0][j]);
    async_copy16(Bg[j], BsB[0][j]);
  }

  const int fr = lane & 15;
  const int fk = (lane >> 4) * 8;
  const int nk = K / BK;

  for (int ki = 0; ki < nk; ki++) {
    const int cur = ki & 1;
    __syncthreads();
    if (ki + 1 < nk) {
      const int k0 = (ki + 1) * BK;
#pragma unroll
      for (int j = 0; j < 2; j++) {
        async_copy16(Ag[j] + k0, AsB[cur ^ 1][j]);
        async_copy16(Bg[j] + k0, BsB[cur ^ 1][j]);
      }
    }
    bfrag a[4], b[4];
#pragma unroll
    for (int i = 0; i < 4; i++) {
      a[i] = *(const bfrag*)&As[cur][wm + i * 16 + fr][fk];
      b[i] = *(const bfrag*)&Bs[cur][wn + i * 16 + fr][fk];
    }
#pragma unroll
    for (int i = 0; i < 4; i++)
#pragma unroll
      for (int j = 0; j < 4; j++)
        acc[i][j] = __builtin_amdgcn_mfma_f32_16x16x32_bf16(a[i], b[j], acc[i][j], 0, 0, 0);
  }

  const int ccol = lane & 15;
  const int crow = (lane >> 4) * 4;
#pragma unroll
  for (int i = 0; i < 4; i++) {
#pragma unroll
    for (int j = 0; j < 4; j++) {
#pragma unroll
      for (int r = 0; r < 4; r++) {
        const size_t gm = m0 + wm + i * 16 + crow + r;
        const size_t gn = n0 + wn + j * 16 + ccol;
        if (CMODE == 2) {
          ((bf16*)Cv)[gm * N + gn] = __float2bfloat16(acc[i][j][r]);
        } else if (CMODE == 1) {
          float* cp = (float*)Cv + gm * N + gn;
          *cp += acc[i][j][r];
        } else {
          ((float*)Cv)[gm * N + gn] = acc[i][j][r];
        }
      }
    }
  }
}

// ---------------------------------------------------------------------------
// BN=64 variant for N=768 GEMMs (wo, wd): grid 384 blocks -> full CU coverage.
// 128x64 tile; waves 2x2, each 64x32 subtile (acc[4][2]).
// ---------------------------------------------------------------------------
template <int CMODE>
__global__ __launch_bounds__(256) void gemm_bf16_n64(
    const bf16* __restrict__ A, const bf16* __restrict__ B,
    void* __restrict__ Cv, int M, int N, int K) {
  __shared__ bf16 As[2][BM][BK];  // 16 KB
  __shared__ bf16 Bs[2][64][BK];  // 8 KB

  const int tid = threadIdx.x;
  const int wave = tid >> 6;
  const int lane = tid & 63;
  const int m0 = blockIdx.y * BM;
  const int n0 = blockIdx.x * 64;
  const int wm = (wave & 1) * 64;
  const int wn = (wave >> 1) * 32;

  f32x4 acc[4][2];
#pragma unroll
  for (int i = 0; i < 4; i++)
#pragma unroll
    for (int j = 0; j < 2; j++) acc[i][j] = (f32x4)(0.f);

  const int lrow = lane >> 2;
  const int lcol = (lane & 3) * 8;
  const bf16* Ag[2]; const bf16* Bg;
  void *AsB[2][2], *BsB[2];
#pragma unroll
  for (int j = 0; j < 2; j++) {
    int c = j * 4 + wave;
    Ag[j] = A + (size_t)(m0 + c * 16 + lrow) * K + lcol;
#pragma unroll
    for (int bf = 0; bf < 2; bf++) AsB[bf][j] = (void*)&As[bf][c * 16][0];
  }
  Bg = B + (size_t)(n0 + wave * 16 + lrow) * K + lcol;
#pragma unroll
  for (int bf = 0; bf < 2; bf++) BsB[bf] = (void*)&Bs[bf][wave * 16][0];

  async_copy16(Ag[0], AsB[0][0]);
  async_copy16(Ag[1], AsB[0][1]);
  async_copy16(Bg, BsB[0]);

  const int fr = lane & 15;
  const int fk = (lane >> 4) * 8;
  const int nk = K / BK;

  for (int ki = 0; ki < nk; ki++) {
    const int cur = ki & 1;
    __syncthreads();
    if (ki + 1 < nk) {
      const int k0 = (ki + 1) * BK;
      async_copy16(Ag[0] + k0, AsB[cur ^ 1][0]);
      async_copy16(Ag[1] + k0, AsB[cur ^ 1][1]);
      async_copy16(Bg + k0, BsB[cur ^ 1]);
    }
    bfrag a[4], b[2];
#pragma unroll
    for (int i = 0; i < 4; i++)
      a[i] = *(const bfrag*)&As[cur][wm + i * 16 + fr][fk];
#pragma unroll
    for (int j = 0; j < 2; j++)
      b[j] = *(const bfrag*)&Bs[cur][wn + j * 16 + fr][fk];
#pragma unroll
    for (int i = 0; i < 4; i++)
#pragma unroll
      for (int j = 0; j < 2; j++)
        acc[i][j] = __builtin_amdgcn_mfma_f32_16x16x32_bf16(a[i], b[j], acc[i][j], 0, 0, 0);
  }

  const int ccol = lane & 15;
  const int crow = (lane >> 4) * 4;
#pragma unroll
  for (int i = 0; i < 4; i++) {
#pragma unroll
    for (int j = 0; j < 2; j++) {
#pragma unroll
      for (int r = 0; r < 4; r++) {
        const size_t gm = m0 + wm + i * 16 + crow + r;
        const size_t gn = n0 + wn + j * 16 + ccol;
        if (CMODE == 2) {
          ((bf16*)Cv)[gm * N + gn] = __float2bfloat16(acc[i][j][r]);
        } else if (CMODE == 1) {
          float* cp = (float*)Cv + gm * N + gn;
          *cp += acc[i][j][r];
        } else {
          ((float*)Cv)[gm * N + gn] = acc[i][j][r];
        }
      }
    }
  }
}

// ---------------------------------------------------------------------------
// Fused gate+up GEMM with silu epilogue (dbuf, 3 staged matrices).
// ---------------------------------------------------------------------------
__global__ __launch_bounds__(256) void gemm_gateup(
    const bf16* __restrict__ A, const bf16* __restrict__ Wg,
    const bf16* __restrict__ Wu, bf16* __restrict__ gu, int M, int N, int K) {
  __shared__ bf16 As[2][BM][BK];
  __shared__ bf16 Gs[2][BN][BK];
  __shared__ bf16 Us[2][BN][BK];

  const int tid = threadIdx.x;
  const int wave = tid >> 6;
  const int lane = tid & 63;
  const int m0 = blockIdx.y * BM;
  const int n0 = blockIdx.x * BN;
  const int wm = (wave & 1) * 64;
  const int wn = (wave >> 1) * 64;

  f32x4 accG[4][4], accU[4][4];
#pragma unroll
  for (int i = 0; i < 4; i++)
#pragma unroll
    for (int j = 0; j < 4; j++) { accG[i][j] = (f32x4)(0.f); accU[i][j] = (f32x4)(0.f); }

  const int lrow = lane >> 2;
  const int lcol = (lane & 3) * 8;
  const bf16 *Ag[2], *Gg[2], *Ug[2];
  void *AsB[2][2], *GsB[2][2], *UsB[2][2];
#pragma unroll
  for (int j = 0; j < 2; j++) {
    int c = j * 4 + wave;
    Ag[j] = A + (size_t)(m0 + c * 16 + lrow) * K + lcol;
    Gg[j] = Wg + (size_t)(n0 + c * 16 + lrow) * K + lcol;
    Ug[j] = Wu + (size_t)(n0 + c * 16 + lrow) * K + lcol;
#pragma unroll
    for (int bf = 0; bf < 2; bf++) {
      AsB[bf][j] = (void*)&As[bf][c * 16][0];
      GsB[bf][j] = (void*)&Gs[bf][c * 16][0];
      UsB[bf][j] = (void*)&Us[bf][c * 16][0];
    }
  }

#pragma unroll
  for (int j = 0; j < 2; j++) {
    async_copy16(Ag[j], AsB[0][j]);
    async_copy16(Gg[j], GsB[0][j]);
    async_copy16(Ug[j], UsB[0][j]);
  }

  const int fr = lane & 15;
  const int fk = (lane >> 4) * 8;
  const int nk = K / BK;

  for (int ki = 0; ki < nk; ki++) {
    const int cur = ki & 1;
    __syncthreads();
    if (ki + 1 < nk) {
      const int k0 = (ki + 1) * BK;
#pragma unroll
      for (int j = 0; j < 2; j++) {
        async_copy16(Ag[j] + k0, AsB[cur ^ 1][j]);
        async_copy16(Gg[j] + k0, GsB[cur ^ 1][j]);
        async_copy16(Ug[j] + k0, UsB[cur ^ 1][j]);
      }
    }
    bfrag a[4], g[4], u[4];
#pragma unroll
    for (int i = 0; i < 4; i++) {
      a[i] = *(const bfrag*)&As[cur][wm + i * 16 + fr][fk];
      g[i] = *(const bfrag*)&Gs[cur][wn + i * 16 + fr][fk];
      u[i] = *(const bfrag*)&Us[cur][wn + i * 16 + fr][fk];
    }
#pragma unroll
    for (int i = 0; i < 4; i++)
#pragma unroll
      for (int j = 0; j < 4; j++) {
        accG[i][j] = __builtin_amdgcn_mfma_f32_16x16x32_bf16(a[i], g[j], accG[i][j], 0, 0, 0);
        accU[i][j] = __builtin_amdgcn_mfma_f32_16x16x32_bf16(a[i], u[j], accU[i][j], 0, 0, 0);
      }
  }

  const int ccol = lane & 15;
  const int crow = (lane >> 4) * 4;
#pragma unroll
  for (int i = 0; i < 4; i++) {
#pragma unroll
    for (int j = 0; j < 4; j++) {
#pragma unroll
      for (int r = 0; r < 4; r++) {
        const size_t gm = m0 + wm + i * 16 + crow + r;
        const size_t gn = n0 + wn + j * 16 + ccol;
        const float gv = accG[i][j][r];
        const float uv = accU[i][j][r];
        const float res = gv / (1.0f + __expf(-gv)) * uv;
        gu[gm * N + gn] = __float2bfloat16(res);
      }
    }
  }
}

// ---------------------------------------------------------------------------
// V transpose pre-pass: vt[b][h][d][s] = qkv[b][s][2D + h*HD + d]
// One block per (64-key tile, h, b); LDS-tiled, conflict-free interleave.
// ---------------------------------------------------------------------------
__global__ __launch_bounds__(256) void transpose_v(
    const bf16* __restrict__ qkv, bf16* __restrict__ vt) {
  __shared__ bf16 T[HD][64];
  const int tid = threadIdx.x;
  const int kb = blockIdx.x * 64;
  const int h = blockIdx.y;
  const int b = blockIdx.z;
  const size_t rstride = 3 * DMODEL;
  const bf16* vsrc = qkv + ((size_t)(b * SEQ + kb)) * rstride + 2 * DMODEL + h * HD;

  if (tid < 192) {
    int p = tid & 31, c = tid >> 5;   // 32 key-pairs x 6 d-chunks
    const bf16* v0 = vsrc + (size_t)(2 * p) * rstride + c * 8;
    uint4 r0 = *(const uint4*)v0;
    uint4 r1 = *(const uint4*)(v0 + rstride);
    const unsigned int* w0 = (const unsigned int*)&r0;
    const unsigned int* w1 = (const unsigned int*)&r1;
#pragma unroll
    for (int i = 0; i < 8; i++) {
      unsigned int lo = (i & 1) ? (w0[i >> 1] >> 16) : (w0[i >> 1] & 0xffffu);
      unsigned int hi = (i & 1) ? (w1[i >> 1] >> 16) : (w1[i >> 1] & 0xffffu);
      *(unsigned int*)&T[c * 8 + i][2 * p] = lo | (hi << 16);
    }
  }
  __syncthreads();
  for (int it = tid; it < HD * 8; it += 256) {
    int d = it >> 3, c = it & 7;
    *(uint4*)(vt + ((size_t)((b * HNUM + h) * HD + d)) * SEQ + kb + c * 8) =
        *(const uint4*)&T[d][c * 8];
  }
}

// ---------------------------------------------------------------------------
// MFMA flash attention, register-prefetched staging.
// K from qkv (row-major), V from pre-transposed vt[b,h,d,s].
// Per tile: publish prefetched regs -> LDS, barrier, issue next tile's
// global loads, then compute (QK MFMA, softmax, P->LDS, PV MFMA).
// ---------------------------------------------------------------------------
#define AQT 64
#define AKT 64
#define ASTR 72

__global__ __launch_bounds__(256, 4) void attn_mfma(
    const bf16* __restrict__ qkv, const bf16* __restrict__ vt,
    const float* __restrict__ log_slopes, bf16* __restrict__ obuf) {
  __shared__ bf16 Qs[AQT][ASTR];
  __shared__ bf16 Ks[AKT][ASTR];
  __shared__ bf16 Vs[HD][ASTR];
  __shared__ bf16 Pt[AQT][ASTR];

  const int tid = threadIdx.x;
  const int wq = tid >> 6;
  const int lane = tid & 63;
  const int l15 = lane & 15;
  const int lh = lane >> 4;
  const int qb = blockIdx.x * AQT;
  const int h = blockIdx.y;
  const int b = blockIdx.z;

  const float scale = 0.14433756729740643f;  // 1/sqrt(48)
  const float slope = __expf(log_slopes[h]);
  const size_t rstride = 3 * DMODEL;
  const bf16* qbase = qkv + ((size_t)(b * SEQ + qb)) * rstride + h * HD;
  const bf16* kbase0 = qkv + ((size_t)b * SEQ) * rstride + DMODEL + h * HD;
  const bf16* vbase0 = vt + ((size_t)((b * HNUM + h) * HD)) * SEQ;

  // staging descriptors: 3 uint4/thread (384 K-entries, then 384 V-entries)
  bf16* ldst[3];
  size_t goff[3];
  bool isK[3];
#pragma unroll
  for (int j = 0; j < 3; j++) {
    int id = tid + j * 256;
    if (id < 384) {
      int r = id / 6, c = id - r * 6;
      ldst[j] = &Ks[r][c * 8];
      goff[j] = (size_t)r * rstride + c * 8;
      isK[j] = true;
    } else {
      id -= 384;
      int d = id >> 3, c = id & 7;
      ldst[j] = &Vs[d][c * 8];
      goff[j] = (size_t)d * SEQ + c * 8;
      isK[j] = false;
    }
  }

  // zero-pad d = 48..63 of Qs, Ks (stage loops never touch it)
  for (int it = tid; it < AQT * 2; it += 256) {
    int r = it >> 1, c = it & 1;
    *(uint4*)&Qs[r][48 + c * 8] = make_uint4(0, 0, 0, 0);
    *(uint4*)&Ks[r][48 + c * 8] = make_uint4(0, 0, 0, 0);
  }
  // stage Q
  for (int it = tid; it < AQT * 6; it += 256) {
    int r = it / 6, c = it - (it / 6) * 6;
    *(uint4*)&Qs[r][c * 8] = *(const uint4*)(qbase + (size_t)r * rstride + c * 8);
  }

  // prefetch tile 0
  uint4 pre[3];
#pragma unroll
  for (int j = 0; j < 3; j++)
    pre[j] = *(const uint4*)((isK[j] ? kbase0 : vbase0) + goff[j]);

  float m[4], l[4];
  f32x4 accO[3];
#pragma unroll
  for (int r = 0; r < 4; r++) { m[r] = -1e30f; l[r] = 0.f; }
#pragma unroll
  for (int t = 0; t < 3; t++) accO[t] = (f32x4)(0.f);

  for (int kb = 0; kb < SEQ; kb += AKT) {
    __syncthreads();  // prior compute done reading Ks/Vs (covers Q/pad on 1st)
    // publish prefetched tile
#pragma unroll
    for (int j = 0; j < 3; j++) *(uint4*)ldst[j] = pre[j];
    __syncthreads();
    // prefetch next tile (consumed after a full compute phase)
    if (kb + AKT < SEQ) {
      const bf16* kb1 = kbase0 + (size_t)(kb + AKT) * rstride;
      const bf16* vb1 = vbase0 + (kb + AKT);
#pragma unroll
      for (int j = 0; j < 3; j++)
        pre[j] = *(const uint4*)((isK[j] ? kb1 : vb1) + goff[j]);
    }

    // QK^T
    f32x4 accS[4];
#pragma unroll
    for (int j = 0; j < 4; j++) accS[j] = (f32x4)(0.f);
#pragma unroll
    for (int ks = 0; ks < 2; ks++) {
      bfrag a = *(const bfrag*)&Qs[wq * 16 + l15][ks * 32 + lh * 8];
#pragma unroll
      for (int j = 0; j < 4; j++) {
        bfrag bk = *(const bfrag*)&Ks[j * 16 + l15][ks * 32 + lh * 8];
        accS[j] = __builtin_amdgcn_mfma_f32_16x16x32_bf16(a, bk, accS[j], 0, 0, 0);
      }
    }

    // bias + online softmax; C-layout: row(q) = lh*4 + r, col(key) = l15
    float ps[4][4];
#pragma unroll
    for (int r = 0; r < 4; r++) {
      const int qg = qb + wq * 16 + lh * 4 + r;
      float s[4];
#pragma unroll
      for (int j = 0; j < 4; j++) {
        const int kg = kb + j * 16 + l15;
        s[j] = accS[j][r] * scale - slope * fabsf((float)(qg - kg));
      }
      float mx = fmaxf(fmaxf(s[0], s[1]), fmaxf(s[2], s[3]));
#pragma unroll
      for (int off = 1; off < 16; off <<= 1) mx = fmaxf(mx, __shfl_xor(mx, off, 64));
      const float mnew = fmaxf(m[r], mx);
      const float corr = __expf(m[r] - mnew);
      float rs = 0.f;
#pragma unroll
      for (int j = 0; j < 4; j++) {
        ps[j][r] = __expf(s[j] - mnew);
        rs += ps[j][r];
      }
#pragma unroll
      for (int off = 1; off < 16; off <<= 1) rs += __shfl_xor(rs, off, 64);
      l[r] = l[r] * corr + rs;
      m[r] = mnew;
#pragma unroll
      for (int t = 0; t < 3; t++) accO[t][r] *= corr;
    }

    // P -> per-wave LDS slice Pt[q][key]
#pragma unroll
    for (int j = 0; j < 4; j++)
#pragma unroll
      for (int r = 0; r < 4; r++)
        Pt[wq * 16 + lh * 4 + r][j * 16 + l15] = __float2bfloat16(ps[j][r]);

    // PV (wave-private Pt rows; in-wave lgkmcnt ordering suffices)
#pragma unroll
    for (int ks = 0; ks < 2; ks++) {
      bfrag pa = *(const bfrag*)&Pt[wq * 16 + l15][ks * 32 + lh * 8];
#pragma unroll
      for (int t = 0; t < 3; t++) {
        bfrag vb = *(const bfrag*)&Vs[t * 16 + l15][ks * 32 + lh * 8];
        accO[t] = __builtin_amdgcn_mfma_f32_16x16x32_bf16(pa, vb, accO[t], 0, 0, 0);
      }
    }
  }

  // epilogue: O / l -> obuf
#pragma unroll
  for (int r = 0; r < 4; r++) {
    const float inv = 1.0f / l[r];
    bf16* op = obuf + ((size_t)(b * SEQ + qb + wq * 16 + lh * 4 + r)) * DMODEL + h * HD;
#pragma unroll
    for (int t = 0; t < 3; t++)
      op[t * 16 + l15] = __float2bfloat16(accO[t][r] * inv);
  }
}

// ---------------------------------------------------------------------------
// launcher
// ---------------------------------------------------------------------------
extern "C" void kernel_launch(void* const* d_in, const int* in_sizes, int n_in,
                              void* d_out, int out_size, void* d_ws, size_t ws_size,
                              hipStream_t stream) {
  const float* cls_tokens = (const float*)d_in[0];
  const float* cls_token  = (const float*)d_in[1];
  const float* log_slopes = (const float*)d_in[2];
  const float* Wqkv = (const float*)d_in[3];
  const float* Wo   = (const float*)d_in[4];
  const float* Wg   = (const float*)d_in[5];
  const float* Wu   = (const float*)d_in[6];
  const float* Wd   = (const float*)d_in[7];
  const float* ln1_w = (const float*)d_in[8];
  const float* ln1_b = (const float*)d_in[9];
  const float* ln2_w = (const float*)d_in[10];
  const float* ln2_b = (const float*)d_in[11];
  const float* fin_w = (const float*)d_in[12];
  const float* fin_b = (const float*)d_in[13];
  float* out = (float*)d_out;

  const size_t ROWS = (size_t)BATCH * SEQ;  // 4096
  char* wsb = (char*)d_ws;
  float* x    = (float*)(wsb);                       // 12,582,912 B
  bf16* qkvb  = (bf16*)(wsb + 12582912);             // 18,874,368 B
  bf16* hb    = (bf16*)(wsb + 31457280);             //  6,291,456 B
  bf16* ob    = (bf16*)(wsb + 37748736);             //  6,291,456 B
  bf16* gub   = (bf16*)(wsb + 44040192);             // 25,165,824 B
  bf16* wbf   = (bf16*)(wsb + 94371840);             // 18,874,368 B
  bf16* vtb   = (bf16*)(wsb + 113246208);            //  6,291,456 B -> 119.5 MB

  bf16* wqkv_b = wbf;
  bf16* wo_b   = wbf + 1769472;
  bf16* wg_b   = wbf + 2359296;
  bf16* wu_b   = wbf + 4718592;
  bf16* wd_b   = wbf + 7077888;

  {
    const size_t total = ROWS * DMODEL;
    concat_kernel<<<(int)((total + 255) / 256), 256, 0, stream>>>(cls_tokens, cls_token, x);
  }

  for (int l = 0; l < LNUM; l++) {
    convert_w_kernel<<<9216, 256, 0, stream>>>(
        Wqkv + (size_t)l * 3 * DMODEL * DMODEL, Wo + (size_t)l * DMODEL * DMODEL,
        Wg + (size_t)l * FFDIM * DMODEL, Wu + (size_t)l * FFDIM * DMODEL,
        Wd + (size_t)l * DMODEL * FFDIM, wbf);

    ln_kernel<bf16><<<(int)ROWS, 256, 0, stream>>>(
        x, hb, ln1_w + l * DMODEL, ln1_b + l * DMODEL, DMODEL, DMODEL);
    gemm_bf16<2><<<dim3(3 * DMODEL / BN, ROWS / BM), 256, 0, stream>>>(
        hb, wqkv_b, qkvb, (int)ROWS, 3 * DMODEL, DMODEL);
    transpose_v<<<dim3(SEQ / 64, HNUM, BATCH), 256, 0, stream>>>(qkvb, vtb);
    attn_mfma<<<dim3(SEQ / AQT, HNUM, BATCH), 256, 0, stream>>>(
        qkvb, vtb, log_slopes, ob);
    gemm_bf16_n64<1><<<dim3(DMODEL / 64, ROWS / BM), 256, 0, stream>>>(
        ob, wo_b, x, (int)ROWS, DMODEL, DMODEL);
    ln_kernel<bf16><<<(int)ROWS, 256, 0, stream>>>(
        x, hb, ln2_w + l * DMODEL, ln2_b + l * DMODEL, DMODEL, DMODEL);
    gemm_gateup<<<dim3(FFDIM / BN, ROWS / BM), 256, 0, stream>>>(
        hb, wg_b, wu_b, gub, (int)ROWS, FFDIM, DMODEL);
    gemm_bf16_n64<1><<<dim3(DMODEL / 64, ROWS / BM), 256, 0, stream>>>(
        gub, wd_b, x, (int)ROWS, DMODEL, FFDIM);
  }

  ln_kernel<float><<<BATCH, 256, 0, stream>>>(x, out, fin_w, fin_b,
                                              (size_t)SEQ * DMODEL, DMODEL);
}